// Round 1
// baseline (772.508 us; speedup 1.0000x reference)
//
#include <hip/hip_runtime.h>
#include <math.h>

// GAT 2-layer: N=50000 nodes, E=800000 edges (+N self loops)
// L1: 512 -> 4 heads x 64, ELU.  L2: 256 -> 1 head x 40, log_softmax.

static __device__ __forceinline__ float leaky(float x){ return x > 0.f ? x : 0.2f*x; }

// ---------------- init: zero degree + cursor ----------------
__global__ void k_init(int* __restrict__ deg, int* __restrict__ cur, int n){
  int i = blockIdx.x*blockDim.x + threadIdx.x;
  if (i < n){ deg[i] = 0; cur[i] = 0; }
}

// ---------------- count in-degree (incl self loops) ----------------
__global__ void k_count(const int* __restrict__ ei, int E, int n, int* __restrict__ deg){
  int i = blockIdx.x*blockDim.x + threadIdx.x;
  int tot = E + n;
  if (i >= tot) return;
  int dst = (i < E) ? ei[E + i] : (i - E);
  atomicAdd(&deg[dst], 1);
}

// ---------------- exclusive scan -> rowstart[0..n] ----------------
__global__ __launch_bounds__(1024) void k_scan(const int* __restrict__ deg, int* __restrict__ rowstart, int n){
  __shared__ int part[1024];
  int t = threadIdx.x;
  int chunk = (n + 1023) >> 10;
  int lo = t*chunk, hi = lo + chunk;
  if (lo > n) lo = n;
  if (hi > n) hi = n;
  int s = 0;
  for (int i=lo;i<hi;++i) s += deg[i];
  part[t] = s;
  __syncthreads();
  for (int off=1; off<1024; off<<=1){
    int v = (t >= off) ? part[t-off] : 0;
    __syncthreads();
    part[t] += v;
    __syncthreads();
  }
  int run = part[t] - s;          // exclusive prefix
  for (int i=lo;i<hi;++i){ rowstart[i] = run; run += deg[i]; }
  if (t == 1023) rowstart[n] = part[1023];
}

// ---------------- scatter edges into CSR (by dst, stores src) ----------------
__global__ void k_fill(const int* __restrict__ ei, int E, int n,
                       const int* __restrict__ rowstart, int* __restrict__ cur, int* __restrict__ csr){
  int i = blockIdx.x*blockDim.x + threadIdx.x;
  int tot = E + n;
  if (i >= tot) return;
  int src, dst;
  if (i < E){ src = ei[i]; dst = ei[E+i]; } else { src = i - E; dst = src; }
  int pos = atomicAdd(&cur[dst], 1);
  csr[rowstart[dst] + pos] = src;
}

// ---------------- GEMM1: [M,512] @ [512,256] -> [M,256], fp32 ----------------
// 128x128 tile, 256 threads, 8x8 micro-tile, K-tile 16.
__global__ __launch_bounds__(256) void k_gemm1(const float* __restrict__ A, const float* __restrict__ B,
                                               float* __restrict__ C, int M){
  __shared__ float As[16][136];   // [kk][r], pad 136 keeps f4 reads aligned
  __shared__ float Bs[16][128];   // [kk][c]
  const int t = threadIdx.x;
  const int row0 = blockIdx.x*128, col0 = blockIdx.y*128;
  const int tx = t & 15, ty = t >> 4;
  float acc[8][8];
  #pragma unroll
  for (int i=0;i<8;i++)
    #pragma unroll
    for (int j=0;j<8;j++) acc[i][j] = 0.f;

  for (int kt=0; kt<512; kt+=16){
    #pragma unroll
    for (int i=0;i<2;i++){                  // A: 128 rows x 16 k = 512 f4
      int f = t + i*256;
      int r = f>>2, k4 = f&3;
      int grow = row0 + r; if (grow >= M) grow = M-1;
      const float4 v = *(const float4*)(A + (size_t)grow*512 + kt + k4*4);
      As[k4*4+0][r] = v.x; As[k4*4+1][r] = v.y; As[k4*4+2][r] = v.z; As[k4*4+3][r] = v.w;
    }
    #pragma unroll
    for (int i=0;i<2;i++){                  // B: 16 k x 128 cols = 512 f4
      int f = t + i*256;
      int kk = f>>5, c4 = f&31;
      *(float4*)&Bs[kk][c4*4] = *(const float4*)(B + (size_t)(kt+kk)*256 + col0 + c4*4);
    }
    __syncthreads();
    #pragma unroll
    for (int kk=0; kk<16; ++kk){
      float a[8], b[8];
      *(float4*)&a[0] = *(const float4*)&As[kk][ty*4];
      *(float4*)&a[4] = *(const float4*)&As[kk][64+ty*4];
      *(float4*)&b[0] = *(const float4*)&Bs[kk][tx*4];
      *(float4*)&b[4] = *(const float4*)&Bs[kk][64+tx*4];
      #pragma unroll
      for (int i=0;i<8;i++)
        #pragma unroll
        for (int j=0;j<8;j++) acc[i][j] += a[i]*b[j];
    }
    __syncthreads();
  }
  #pragma unroll
  for (int i=0;i<8;i++){
    int r = row0 + ((i<4) ? (ty*4+i) : (64+ty*4+(i-4)));
    if (r < M){
      float4 v0 = make_float4(acc[i][0],acc[i][1],acc[i][2],acc[i][3]);
      float4 v1 = make_float4(acc[i][4],acc[i][5],acc[i][6],acc[i][7]);
      *(float4*)(C + (size_t)r*256 + col0 + tx*4)      = v0;
      *(float4*)(C + (size_t)r*256 + col0 + 64 + tx*4) = v1;
    }
  }
}

// ---------------- attention coefficients L1: a_s/a_d [N,4] ----------------
__global__ __launch_bounds__(256) void k_att1(const float* __restrict__ h1,
    const float* __restrict__ sw, const float* __restrict__ dw,
    float* __restrict__ as1, float* __restrict__ ad1, int n){
  int lane = threadIdx.x & 63;
  int node = blockIdx.x*4 + (threadIdx.x >> 6);
  if (node >= n) return;
  float4 hv = *(const float4*)(h1 + (size_t)node*256 + lane*4);
  float4 sv = *(const float4*)(sw + lane*4);
  float4 dv = *(const float4*)(dw + lane*4);
  float ps = hv.x*sv.x + hv.y*sv.y + hv.z*sv.z + hv.w*sv.w;
  float pd = hv.x*dv.x + hv.y*dv.y + hv.z*dv.z + hv.w*dv.w;
  #pragma unroll
  for (int o=1;o<16;o<<=1){ ps += __shfl_xor(ps,o); pd += __shfl_xor(pd,o); }
  if ((lane & 15) == 0){
    int h = lane >> 4;
    as1[node*4+h] = ps;
    ad1[node*4+h] = pd;
  }
}

// ---------------- aggregation L1 (softmax over in-edges) + bias + ELU ----------------
__global__ __launch_bounds__(256) void k_agg1(const float* __restrict__ h1,
    const float* __restrict__ as1, const float* __restrict__ ad1,
    const int* __restrict__ rowstart, const int* __restrict__ csr,
    const float* __restrict__ b1, float* __restrict__ hact, int n){
  int lane = threadIdx.x & 63;
  int node = blockIdx.x*4 + (threadIdx.x >> 6);
  if (node >= n) return;
  int lo = rowstart[node], hi = rowstart[node+1];
  float4 adv = *(const float4*)(ad1 + node*4);
  float m0=-INFINITY, m1=-INFINITY, m2=-INFINITY, m3=-INFINITY;
  for (int e = lo + lane; e < hi; e += 64){
    int s = csr[e];
    float4 asv = *(const float4*)(as1 + s*4);
    m0 = fmaxf(m0, leaky(asv.x + adv.x));
    m1 = fmaxf(m1, leaky(asv.y + adv.y));
    m2 = fmaxf(m2, leaky(asv.z + adv.z));
    m3 = fmaxf(m3, leaky(asv.w + adv.w));
  }
  #pragma unroll
  for (int o=1;o<64;o<<=1){
    m0 = fmaxf(m0, __shfl_xor(m0,o));
    m1 = fmaxf(m1, __shfl_xor(m1,o));
    m2 = fmaxf(m2, __shfl_xor(m2,o));
    m3 = fmaxf(m3, __shfl_xor(m3,o));
  }
  int h = lane >> 4;                         // head of this lane's 4 channels
  float mh  = (h==0)?m0:(h==1)?m1:(h==2)?m2:m3;
  float adh = (h==0)?adv.x:(h==1)?adv.y:(h==2)?adv.z:adv.w;
  float ax=0.f, ay=0.f, az=0.f, aw=0.f, ssum=0.f;
  for (int e = lo; e < hi; ++e){
    int s = csr[e];
    float ex = __expf(leaky(as1[s*4+h] + adh) - mh);
    float4 hv = *(const float4*)(h1 + (size_t)s*256 + lane*4);
    ax += ex*hv.x; ay += ex*hv.y; az += ex*hv.z; aw += ex*hv.w;
    ssum += ex;
  }
  float inv = 1.f/(ssum + 1e-16f);
  float4 bv = *(const float4*)(b1 + lane*4);
  float o0 = ax*inv + bv.x, o1 = ay*inv + bv.y, o2 = az*inv + bv.z, o3 = aw*inv + bv.w;
  float4 r;
  r.x = o0 > 0.f ? o0 : expm1f(o0);
  r.y = o1 > 0.f ? o1 : expm1f(o1);
  r.z = o2 > 0.f ? o2 : expm1f(o2);
  r.w = o3 > 0.f ? o3 : expm1f(o3);
  *(float4*)(hact + (size_t)node*256 + lane*4) = r;
}

// ---------------- GEMM2: [M,256] @ [256,40] -> [M,40], fp32 ----------------
__global__ __launch_bounds__(256) void k_gemm2(const float* __restrict__ A, const float* __restrict__ B,
                                               float* __restrict__ C, int M){
  __shared__ float Xl[32][129];       // pad -> conflict-free column reads
  __shared__ float Wl[128*40];
  int t = threadIdx.x;
  int row0 = blockIdx.x*32;
  int r = t & 31, g = t >> 5;         // g in 0..7 -> cols g*5 .. g*5+4
  float acc[5] = {0,0,0,0,0};
  for (int kt=0; kt<256; kt+=128){
    for (int i=t; i<1280; i+=256)
      *(float4*)&Wl[i*4] = *(const float4*)(B + kt*40 + i*4);
    for (int i=t; i<1024; i+=256){
      int rr = i >> 5, k4 = i & 31;
      int grow = row0 + rr; if (grow >= M) grow = M-1;
      float4 v = *(const float4*)(A + (size_t)grow*256 + kt + k4*4);
      Xl[rr][k4*4+0]=v.x; Xl[rr][k4*4+1]=v.y; Xl[rr][k4*4+2]=v.z; Xl[rr][k4*4+3]=v.w;
    }
    __syncthreads();
    #pragma unroll 4
    for (int k=0;k<128;++k){
      float a = Xl[r][k];
      const float* w = &Wl[k*40 + g*5];
      #pragma unroll
      for (int j=0;j<5;++j) acc[j] += a * w[j];
    }
    __syncthreads();
  }
  int grow = row0 + r;
  if (grow < M){
    #pragma unroll
    for (int j=0;j<5;++j) C[(size_t)grow*40 + g*5 + j] = acc[j];
  }
}

// ---------------- attention coefficients L2: a_s/a_d [N] ----------------
__global__ __launch_bounds__(256) void k_att2(const float* __restrict__ h2,
    const float* __restrict__ sw, const float* __restrict__ dw,
    float* __restrict__ as2, float* __restrict__ ad2, int n){
  int lane = threadIdx.x & 63;
  int node = blockIdx.x*4 + (threadIdx.x >> 6);
  if (node >= n) return;
  bool act = lane < 40;
  float hv = act ? h2[(size_t)node*40 + lane] : 0.f;
  float ps = act ? hv * sw[lane] : 0.f;
  float pd = act ? hv * dw[lane] : 0.f;
  #pragma unroll
  for (int o=1;o<64;o<<=1){ ps += __shfl_xor(ps,o); pd += __shfl_xor(pd,o); }
  if (lane == 0){ as2[node] = ps; ad2[node] = pd; }
}

// ---------------- aggregation L2 + bias + log_softmax -> out ----------------
__global__ __launch_bounds__(256) void k_agg2(const float* __restrict__ h2,
    const float* __restrict__ as2, const float* __restrict__ ad2,
    const int* __restrict__ rowstart, const int* __restrict__ csr,
    const float* __restrict__ b2, float* __restrict__ out, int n){
  int lane = threadIdx.x & 63;
  int node = blockIdx.x*4 + (threadIdx.x >> 6);
  if (node >= n) return;
  int lo = rowstart[node], hi = rowstart[node+1];
  float adn = ad2[node];
  float m = -INFINITY;
  for (int e = lo + lane; e < hi; e += 64){
    int s = csr[e];
    m = fmaxf(m, leaky(as2[s] + adn));
  }
  #pragma unroll
  for (int o=1;o<64;o<<=1) m = fmaxf(m, __shfl_xor(m,o));
  bool act = lane < 40;
  float acc = 0.f, ssum = 0.f;
  for (int e = lo; e < hi; ++e){
    int s = csr[e];
    float ex = __expf(leaky(as2[s] + adn) - m);
    ssum += ex;
    float hv = act ? h2[(size_t)s*40 + lane] : 0.f;
    acc += ex*hv;
  }
  float ov = acc/(ssum + 1e-16f) + (act ? b2[lane] : 0.f);
  float v = act ? ov : -INFINITY;
  float mx = v;
  #pragma unroll
  for (int o=1;o<64;o<<=1) mx = fmaxf(mx, __shfl_xor(mx,o));
  float ev = act ? __expf(ov - mx) : 0.f;
  float se = ev;
  #pragma unroll
  for (int o=1;o<64;o<<=1) se += __shfl_xor(se,o);
  if (act) out[(size_t)node*40 + lane] = (ov - mx) - __logf(se);
}

extern "C" void kernel_launch(void* const* d_in, const int* in_sizes, int n_in,
                              void* d_out, int out_size, void* d_ws, size_t ws_size,
                              hipStream_t stream){
  const float* x   = (const float*)d_in[0];
  const int*   ei  = (const int*)d_in[1];     // [2,E] int32 (harness contract)
  const float* W1  = (const float*)d_in[2];
  const float* s1w = (const float*)d_in[3];
  const float* d1w = (const float*)d_in[4];
  const float* b1  = (const float*)d_in[5];
  const float* W2  = (const float*)d_in[6];
  const float* s2w = (const float*)d_in[7];
  const float* d2w = (const float*)d_in[8];
  const float* b2  = (const float*)d_in[9];
  float* out = (float*)d_out;

  const int N  = in_sizes[0] / 512;
  const int E  = in_sizes[1] / 2;
  const int Et = E + N;

  // workspace carve-out (~112 MB)
  float* f = (float*)d_ws;
  float* h1   = f;  f += (size_t)N*256;
  float* hact = f;  f += (size_t)N*256;
  float* h2   = h1;                 // alias: h1 dead after k_agg1
  float* as1  = f;  f += (size_t)N*4;
  float* ad1  = f;  f += (size_t)N*4;
  float* as2  = f;  f += N;
  float* ad2  = f;  f += N;
  int* ip = (int*)f;
  int* rowstart = ip;  ip += (N + 4) & ~3;
  int* deg      = ip;  ip += N;
  int* cur      = ip;  ip += N;
  int* csr      = ip;  ip += Et;

  int nb4 = (N + 3) / 4;
  k_init <<<(N+255)/256, 256, 0, stream>>>(deg, cur, N);
  k_count<<<(Et+255)/256, 256, 0, stream>>>(ei, E, N, deg);
  k_scan <<<1, 1024, 0, stream>>>(deg, rowstart, N);
  k_fill <<<(Et+255)/256, 256, 0, stream>>>(ei, E, N, rowstart, cur, csr);
  k_gemm1<<<dim3((N+127)/128, 2), 256, 0, stream>>>(x, W1, h1, N);
  k_att1 <<<nb4, 256, 0, stream>>>(h1, s1w, d1w, as1, ad1, N);
  k_agg1 <<<nb4, 256, 0, stream>>>(h1, as1, ad1, rowstart, csr, b1, hact, N);
  k_gemm2<<<(N+31)/32, 256, 0, stream>>>(hact, W2, h2, N);
  k_att2 <<<nb4, 256, 0, stream>>>(h2, s2w, d2w, as2, ad2, N);
  k_agg2 <<<nb4, 256, 0, stream>>>(h2, as2, ad2, rowstart, csr, b2, out, N);
}

// Round 2
// 659.831 us; speedup vs baseline: 1.1708x; 1.1708x over previous
//
#include <hip/hip_runtime.h>
#include <math.h>
#include <stdint.h>

// GAT 2-layer: N=50000 nodes, E=800000 edges (+N self loops)
// L1: 512 -> 4 heads x 64 (bf16 MFMA GEMM), ELU.  L2: 256 -> 1 head x 40, log_softmax.

typedef short bf16x8 __attribute__((ext_vector_type(8)));
typedef float f32x4  __attribute__((ext_vector_type(4)));

static __device__ __forceinline__ float leaky(float x){ return x > 0.f ? x : 0.2f*x; }
static __device__ __forceinline__ unsigned short f2bf(float f){
  uint32_t u = __float_as_uint(f);
  uint32_t r = u + 0x7fffu + ((u >> 16) & 1u);   // RNE
  return (unsigned short)(r >> 16);
}

// ---------------- convert x -> bf16 (vectorized) ----------------
__global__ void k_cvt_x(const float* __restrict__ x, unsigned short* __restrict__ xb, int n4){
  int i = blockIdx.x*blockDim.x + threadIdx.x;
  if (i >= n4) return;
  float4 v = ((const float4*)x)[i];
  ushort4 o; o.x=f2bf(v.x); o.y=f2bf(v.y); o.z=f2bf(v.z); o.w=f2bf(v.w);
  ((ushort4*)xb)[i] = o;
}

// ---------------- convert+transpose W1[512][256] -> w1t[256][512] bf16 ----------------
__global__ void k_cvt_w(const float* __restrict__ W, unsigned short* __restrict__ wt){
  int i = blockIdx.x*blockDim.x + threadIdx.x;   // 0..131071
  if (i >= 512*256) return;
  int k = i >> 8, n = i & 255;
  wt[n*512 + k] = f2bf(W[i]);
}

// ---------------- init: zero degree + cursor ----------------
__global__ void k_init(int* __restrict__ deg, int* __restrict__ cur, int n){
  int i = blockIdx.x*blockDim.x + threadIdx.x;
  if (i < n){ deg[i] = 0; cur[i] = 0; }
}

// ---------------- count in-degree (incl self loops) ----------------
__global__ void k_count(const int* __restrict__ ei, int E, int n, int* __restrict__ deg){
  int i = blockIdx.x*blockDim.x + threadIdx.x;
  int tot = E + n;
  if (i >= tot) return;
  int dst = (i < E) ? ei[E + i] : (i - E);
  atomicAdd(&deg[dst], 1);
}

// ---------------- exclusive scan -> rowstart[0..n] ----------------
__global__ __launch_bounds__(1024) void k_scan(const int* __restrict__ deg, int* __restrict__ rowstart, int n){
  __shared__ int part[1024];
  int t = threadIdx.x;
  int chunk = (n + 1023) >> 10;
  int lo = t*chunk, hi = lo + chunk;
  if (lo > n) lo = n;
  if (hi > n) hi = n;
  int s = 0;
  for (int i=lo;i<hi;++i) s += deg[i];
  part[t] = s;
  __syncthreads();
  for (int off=1; off<1024; off<<=1){
    int v = (t >= off) ? part[t-off] : 0;
    __syncthreads();
    part[t] += v;
    __syncthreads();
  }
  int run = part[t] - s;          // exclusive prefix
  for (int i=lo;i<hi;++i){ rowstart[i] = run; run += deg[i]; }
  if (t == 1023) rowstart[n] = part[1023];
}

// ---------------- scatter edges into CSR (by dst, stores src) ----------------
__global__ void k_fill(const int* __restrict__ ei, int E, int n,
                       const int* __restrict__ rowstart, int* __restrict__ cur, int* __restrict__ csr){
  int i = blockIdx.x*blockDim.x + threadIdx.x;
  int tot = E + n;
  if (i >= tot) return;
  int src, dst;
  if (i < E){ src = ei[i]; dst = ei[E+i]; } else { src = i - E; dst = src; }
  int pos = atomicAdd(&cur[dst], 1);
  csr[rowstart[dst] + pos] = src;
}

// ---------------- GEMM1 (bf16 MFMA): xb[M,512] @ w1t[256,512]^T -> C[M,256] fp32 ----
// 128x128 tile, 4 waves of 64x64, BK=32, global_load_lds(16B) staging.
// LDS layout [kq][row][8 bf16]: 16B chunks contiguous in global AND fragment-read
// friendly (bank stride 16B -> 2-way conflict = free).
__global__ __launch_bounds__(256) void k_gemm1_mfma(const unsigned short* __restrict__ A,
                                                    const unsigned short* __restrict__ BT,
                                                    float* __restrict__ C, int M){
  __shared__ __align__(16) unsigned short lA[4*128*8];  // 8 KB
  __shared__ __align__(16) unsigned short lB[4*128*8];  // 8 KB
  const int t = threadIdx.x;
  const int lane = t & 63, w = t >> 6;
  const int wx = w & 1, wy = w >> 1;
  const int row0 = blockIdx.x * 128, col0 = blockIdx.y * 128;

  f32x4 acc[4][4];
  #pragma unroll
  for (int i=0;i<4;i++)
    #pragma unroll
    for (int j=0;j<4;j++)
      #pragma unroll
      for (int r=0;r<4;r++) acc[i][j][r] = 0.f;

  // staging chunk ids for this thread: c0 = t, c1 = t + 256  (512 chunks/tile)
  const int c0 = t, c1 = t + 256;
  const int r0 = c0 & 127, kq0 = c0 >> 7;
  const int r1 = c1 & 127, kq1 = c1 >> 7;
  const size_t gA0 = (size_t)min(row0 + r0, M-1)*512 + kq0*8;
  const size_t gA1 = (size_t)min(row0 + r1, M-1)*512 + kq1*8;
  const size_t gB0 = (size_t)(col0 + r0)*512 + kq0*8;
  const size_t gB1 = (size_t)(col0 + r1)*512 + kq1*8;

  const int kq = lane >> 4, li = lane & 15;

  for (int kt = 0; kt < 512; kt += 32){
    __builtin_amdgcn_global_load_lds((const __attribute__((address_space(1))) void*)(A + gA0 + kt),
        (__attribute__((address_space(3))) void*)&lA[c0*8], 16, 0, 0);
    __builtin_amdgcn_global_load_lds((const __attribute__((address_space(1))) void*)(A + gA1 + kt),
        (__attribute__((address_space(3))) void*)&lA[c1*8], 16, 0, 0);
    __builtin_amdgcn_global_load_lds((const __attribute__((address_space(1))) void*)(BT + gB0 + kt),
        (__attribute__((address_space(3))) void*)&lB[c0*8], 16, 0, 0);
    __builtin_amdgcn_global_load_lds((const __attribute__((address_space(1))) void*)(BT + gB1 + kt),
        (__attribute__((address_space(3))) void*)&lB[c1*8], 16, 0, 0);
    __syncthreads();   // drains vmcnt -> tile resident

    bf16x8 af[4], bfr[4];
    #pragma unroll
    for (int i=0;i<4;i++){
      af[i]  = *(const bf16x8*)&lA[(kq*128 + wx*64 + i*16 + li)*8];
      bfr[i] = *(const bf16x8*)&lB[(kq*128 + wy*64 + i*16 + li)*8];
    }
    #pragma unroll
    for (int i=0;i<4;i++)
      #pragma unroll
      for (int j=0;j<4;j++)
        acc[i][j] = __builtin_amdgcn_mfma_f32_16x16x32_bf16(af[i], bfr[j], acc[i][j], 0, 0, 0);
    __syncthreads();
  }

  // epilogue: C/D map col=lane&15, row=(lane>>4)*4+reg [m89]
  #pragma unroll
  for (int i=0;i<4;i++){
    #pragma unroll
    for (int r=0;r<4;r++){
      int row = row0 + wx*64 + i*16 + kq*4 + r;
      if (row < M){
        #pragma unroll
        for (int j=0;j<4;j++)
          C[(size_t)row*256 + col0 + wy*64 + j*16 + li] = acc[i][j][r];
      }
    }
  }
}

// ---------------- attention coefficients L1: a_s/a_d [N,4] ----------------
__global__ __launch_bounds__(256) void k_att1(const float* __restrict__ h1,
    const float* __restrict__ sw, const float* __restrict__ dw,
    float* __restrict__ as1, float* __restrict__ ad1, int n){
  int lane = threadIdx.x & 63;
  int node = blockIdx.x*4 + (threadIdx.x >> 6);
  if (node >= n) return;
  float4 hv = *(const float4*)(h1 + (size_t)node*256 + lane*4);
  float4 sv = *(const float4*)(sw + lane*4);
  float4 dv = *(const float4*)(dw + lane*4);
  float ps = hv.x*sv.x + hv.y*sv.y + hv.z*sv.z + hv.w*sv.w;
  float pd = hv.x*dv.x + hv.y*dv.y + hv.z*dv.z + hv.w*dv.w;
  #pragma unroll
  for (int o=1;o<16;o<<=1){ ps += __shfl_xor(ps,o); pd += __shfl_xor(pd,o); }
  if ((lane & 15) == 0){
    int h = lane >> 4;
    as1[node*4+h] = ps;
    ad1[node*4+h] = pd;
  }
}

// ---------------- aggregation L1 (softmax over in-edges) + bias + ELU ----------------
__global__ __launch_bounds__(256) void k_agg1(const float* __restrict__ h1,
    const float* __restrict__ as1, const float* __restrict__ ad1,
    const int* __restrict__ rowstart, const int* __restrict__ csr,
    const float* __restrict__ b1, float* __restrict__ hact, int n){
  int lane = threadIdx.x & 63;
  int node = blockIdx.x*4 + (threadIdx.x >> 6);
  if (node >= n) return;
  int lo = rowstart[node], hi = rowstart[node+1];
  float4 adv = *(const float4*)(ad1 + node*4);
  float m0=-INFINITY, m1=-INFINITY, m2=-INFINITY, m3=-INFINITY;
  for (int e = lo + lane; e < hi; e += 64){
    int s = csr[e];
    float4 asv = *(const float4*)(as1 + s*4);
    m0 = fmaxf(m0, leaky(asv.x + adv.x));
    m1 = fmaxf(m1, leaky(asv.y + adv.y));
    m2 = fmaxf(m2, leaky(asv.z + adv.z));
    m3 = fmaxf(m3, leaky(asv.w + adv.w));
  }
  #pragma unroll
  for (int o=1;o<64;o<<=1){
    m0 = fmaxf(m0, __shfl_xor(m0,o));
    m1 = fmaxf(m1, __shfl_xor(m1,o));
    m2 = fmaxf(m2, __shfl_xor(m2,o));
    m3 = fmaxf(m3, __shfl_xor(m3,o));
  }
  int h = lane >> 4;                         // head of this lane's 4 channels
  float mh  = (h==0)?m0:(h==1)?m1:(h==2)?m2:m3;
  float adh = (h==0)?adv.x:(h==1)?adv.y:(h==2)?adv.z:adv.w;
  float ax=0.f, ay=0.f, az=0.f, aw=0.f, ssum=0.f;
  int e = lo;
  for (; e + 1 < hi; e += 2){                // 2-edge unroll: 2x loads in flight
    int s0 = csr[e], s1 = csr[e+1];
    float x0 = __expf(leaky(as1[s0*4+h] + adh) - mh);
    float x1 = __expf(leaky(as1[s1*4+h] + adh) - mh);
    float4 v0 = *(const float4*)(h1 + (size_t)s0*256 + lane*4);
    float4 v1 = *(const float4*)(h1 + (size_t)s1*256 + lane*4);
    ax += x0*v0.x + x1*v1.x;
    ay += x0*v0.y + x1*v1.y;
    az += x0*v0.z + x1*v1.z;
    aw += x0*v0.w + x1*v1.w;
    ssum += x0 + x1;
  }
  if (e < hi){
    int s0 = csr[e];
    float x0 = __expf(leaky(as1[s0*4+h] + adh) - mh);
    float4 v0 = *(const float4*)(h1 + (size_t)s0*256 + lane*4);
    ax += x0*v0.x; ay += x0*v0.y; az += x0*v0.z; aw += x0*v0.w;
    ssum += x0;
  }
  float inv = 1.f/(ssum + 1e-16f);
  float4 bv = *(const float4*)(b1 + lane*4);
  float o0 = ax*inv + bv.x, o1 = ay*inv + bv.y, o2 = az*inv + bv.z, o3 = aw*inv + bv.w;
  float4 r;
  r.x = o0 > 0.f ? o0 : expm1f(o0);
  r.y = o1 > 0.f ? o1 : expm1f(o1);
  r.z = o2 > 0.f ? o2 : expm1f(o2);
  r.w = o3 > 0.f ? o3 : expm1f(o3);
  *(float4*)(hact + (size_t)node*256 + lane*4) = r;
}

// ---------------- GEMM2: [M,256] @ [256,40] -> [M,40], fp32 ----------------
__global__ __launch_bounds__(256) void k_gemm2(const float* __restrict__ A, const float* __restrict__ B,
                                               float* __restrict__ C, int M){
  __shared__ float Xl[32][129];       // pad -> conflict-free column reads
  __shared__ float Wl[128*40];
  int t = threadIdx.x;
  int row0 = blockIdx.x*32;
  int r = t & 31, g = t >> 5;         // g in 0..7 -> cols g*5 .. g*5+4
  float acc[5] = {0,0,0,0,0};
  for (int kt=0; kt<256; kt+=128){
    for (int i=t; i<1280; i+=256)
      *(float4*)&Wl[i*4] = *(const float4*)(B + kt*40 + i*4);
    for (int i=t; i<1024; i+=256){
      int rr = i >> 5, k4 = i & 31;
      int grow = row0 + rr; if (grow >= M) grow = M-1;
      float4 v = *(const float4*)(A + (size_t)grow*256 + kt + k4*4);
      Xl[rr][k4*4+0]=v.x; Xl[rr][k4*4+1]=v.y; Xl[rr][k4*4+2]=v.z; Xl[rr][k4*4+3]=v.w;
    }
    __syncthreads();
    #pragma unroll 4
    for (int k=0;k<128;++k){
      float a = Xl[r][k];
      const float* w = &Wl[k*40 + g*5];
      #pragma unroll
      for (int j=0;j<5;++j) acc[j] += a * w[j];
    }
    __syncthreads();
  }
  int grow = row0 + r;
  if (grow < M){
    #pragma unroll
    for (int j=0;j<5;++j) C[(size_t)grow*40 + g*5 + j] = acc[j];
  }
}

// ---------------- attention coefficients L2: a_s/a_d [N] ----------------
__global__ __launch_bounds__(256) void k_att2(const float* __restrict__ h2,
    const float* __restrict__ sw, const float* __restrict__ dw,
    float* __restrict__ as2, float* __restrict__ ad2, int n){
  int lane = threadIdx.x & 63;
  int node = blockIdx.x*4 + (threadIdx.x >> 6);
  if (node >= n) return;
  bool act = lane < 40;
  float hv = act ? h2[(size_t)node*40 + lane] : 0.f;
  float ps = act ? hv * sw[lane] : 0.f;
  float pd = act ? hv * dw[lane] : 0.f;
  #pragma unroll
  for (int o=1;o<64;o<<=1){ ps += __shfl_xor(ps,o); pd += __shfl_xor(pd,o); }
  if (lane == 0){ as2[node] = ps; ad2[node] = pd; }
}

// ---------------- aggregation L2 + bias + log_softmax -> out ----------------
__global__ __launch_bounds__(256) void k_agg2(const float* __restrict__ h2,
    const float* __restrict__ as2, const float* __restrict__ ad2,
    const int* __restrict__ rowstart, const int* __restrict__ csr,
    const float* __restrict__ b2, float* __restrict__ out, int n){
  int lane = threadIdx.x & 63;
  int node = blockIdx.x*4 + (threadIdx.x >> 6);
  if (node >= n) return;
  int lo = rowstart[node], hi = rowstart[node+1];
  float adn = ad2[node];
  float m = -INFINITY;
  for (int e = lo + lane; e < hi; e += 64){
    int s = csr[e];
    m = fmaxf(m, leaky(as2[s] + adn));
  }
  #pragma unroll
  for (int o=1;o<64;o<<=1) m = fmaxf(m, __shfl_xor(m,o));
  bool act = lane < 40;
  float acc = 0.f, ssum = 0.f;
  for (int e = lo; e < hi; ++e){
    int s = csr[e];
    float ex = __expf(leaky(as2[s] + adn) - m);
    ssum += ex;
    float hv = act ? h2[(size_t)s*40 + lane] : 0.f;
    acc += ex*hv;
  }
  float ov = acc/(ssum + 1e-16f) + (act ? b2[lane] : 0.f);
  float v = act ? ov : -INFINITY;
  float mx = v;
  #pragma unroll
  for (int o=1;o<64;o<<=1) mx = fmaxf(mx, __shfl_xor(mx,o));
  float ev = act ? __expf(ov - mx) : 0.f;
  float se = ev;
  #pragma unroll
  for (int o=1;o<64;o<<=1) se += __shfl_xor(se,o);
  if (act) out[(size_t)node*40 + lane] = (ov - mx) - __logf(se);
}

extern "C" void kernel_launch(void* const* d_in, const int* in_sizes, int n_in,
                              void* d_out, int out_size, void* d_ws, size_t ws_size,
                              hipStream_t stream){
  const float* x   = (const float*)d_in[0];
  const int*   ei  = (const int*)d_in[1];     // [2,E] int32 (harness contract)
  const float* W1  = (const float*)d_in[2];
  const float* s1w = (const float*)d_in[3];
  const float* d1w = (const float*)d_in[4];
  const float* b1  = (const float*)d_in[5];
  const float* W2  = (const float*)d_in[6];
  const float* s2w = (const float*)d_in[7];
  const float* d2w = (const float*)d_in[8];
  const float* b2  = (const float*)d_in[9];
  float* out = (float*)d_out;

  const int N  = in_sizes[0] / 512;
  const int E  = in_sizes[1] / 2;
  const int Et = E + N;

  // workspace carve-out (~113 MB)
  float* f = (float*)d_ws;
  float* h1   = f;  f += (size_t)N*256;
  float* hact = f;  f += (size_t)N*256;
  float* h2   = h1;                       // alias: h1 dead after k_agg1
  unsigned short* xb = (unsigned short*)hact;  // alias: xb dead before hact written
  float* as1  = f;  f += (size_t)N*4;
  float* ad1  = f;  f += (size_t)N*4;
  float* as2  = f;  f += N;
  float* ad2  = f;  f += N;
  unsigned short* w1t = (unsigned short*)f;  f += 256*512/2;   // [256][512] bf16
  int* ip = (int*)f;
  int* rowstart = ip;  ip += (N + 4) & ~3;
  int* deg      = ip;  ip += N;
  int* cur      = ip;  ip += N;
  int* csr      = ip;  ip += Et;

  int nb4 = (N + 3) / 4;
  int n4  = (N*512)/4;
  k_cvt_x<<<(n4+255)/256, 256, 0, stream>>>(x, xb, n4);
  k_cvt_w<<<512, 256, 0, stream>>>(W1, w1t);
  k_init <<<(N+255)/256, 256, 0, stream>>>(deg, cur, N);
  k_count<<<(Et+255)/256, 256, 0, stream>>>(ei, E, N, deg);
  k_scan <<<1, 1024, 0, stream>>>(deg, rowstart, N);
  k_fill <<<(Et+255)/256, 256, 0, stream>>>(ei, E, N, rowstart, cur, csr);
  k_gemm1_mfma<<<dim3((N+127)/128, 2), 256, 0, stream>>>(xb, w1t, h1, N);
  k_att1 <<<nb4, 256, 0, stream>>>(h1, s1w, d1w, as1, ad1, N);
  k_agg1 <<<nb4, 256, 0, stream>>>(h1, as1, ad1, rowstart, csr, b1, hact, N);
  k_gemm2<<<(N+31)/32, 256, 0, stream>>>(hact, W2, h2, N);
  k_att2 <<<nb4, 256, 0, stream>>>(h2, s2w, d2w, as2, ad2, N);
  k_agg2 <<<nb4, 256, 0, stream>>>(h2, as2, ad2, rowstart, csr, b2, out, N);
}

// Round 3
// 589.708 us; speedup vs baseline: 1.3100x; 1.1189x over previous
//
#include <hip/hip_runtime.h>
#include <math.h>
#include <stdint.h>

// GAT 2-layer: N=50000 nodes, E=800000 edges (+N self loops)
// L1: 512 -> 4 heads x 64 (bf16 MFMA GEMM), ELU.  L2: 256 -> 1 head x 40, log_softmax.
// All intermediate node features (h1, hact, h2) stored bf16; accumulation fp32.

typedef short bf16x8 __attribute__((ext_vector_type(8)));
typedef float f32x4  __attribute__((ext_vector_type(4)));

static __device__ __forceinline__ float leaky(float x){ return x > 0.f ? x : 0.2f*x; }
static __device__ __forceinline__ unsigned short f2bf(float f){
  uint32_t u = __float_as_uint(f);
  uint32_t r = u + 0x7fffu + ((u >> 16) & 1u);   // RNE
  return (unsigned short)(r >> 16);
}
static __device__ __forceinline__ float bf2f(unsigned short u){
  return __uint_as_float(((uint32_t)u) << 16);
}

// ---------------- convert x -> bf16 (vectorized) ----------------
__global__ void k_cvt_x(const float* __restrict__ x, unsigned short* __restrict__ xb, int n4){
  int i = blockIdx.x*blockDim.x + threadIdx.x;
  if (i >= n4) return;
  float4 v = ((const float4*)x)[i];
  ushort4 o; o.x=f2bf(v.x); o.y=f2bf(v.y); o.z=f2bf(v.z); o.w=f2bf(v.w);
  ((ushort4*)xb)[i] = o;
}

// ---------------- convert+transpose W1[512][256] -> w1t[256][512] bf16 ----------------
__global__ void k_cvt_w(const float* __restrict__ W, unsigned short* __restrict__ wt){
  int i = blockIdx.x*blockDim.x + threadIdx.x;   // 0..131071
  if (i >= 512*256) return;
  int k = i >> 8, n = i & 255;
  wt[n*512 + k] = f2bf(W[i]);
}

// ---------------- count in-degree (incl self loops) ----------------
__global__ void k_count(const int* __restrict__ ei, int E, int n, int* __restrict__ deg){
  int i = blockIdx.x*blockDim.x + threadIdx.x;
  int tot = E + n;
  if (i >= tot) return;
  int dst = (i < E) ? ei[E + i] : (i - E);
  atomicAdd(&deg[dst], 1);
}

// ---------------- exclusive scan -> rowstart[0..n] ----------------
__global__ __launch_bounds__(1024) void k_scan(const int* __restrict__ deg, int* __restrict__ rowstart, int n){
  __shared__ int part[1024];
  int t = threadIdx.x;
  int chunk = (n + 1023) >> 10;
  int lo = t*chunk, hi = lo + chunk;
  if (lo > n) lo = n;
  if (hi > n) hi = n;
  int s = 0;
  for (int i=lo;i<hi;++i) s += deg[i];
  part[t] = s;
  __syncthreads();
  for (int off=1; off<1024; off<<=1){
    int v = (t >= off) ? part[t-off] : 0;
    __syncthreads();
    part[t] += v;
    __syncthreads();
  }
  int run = part[t] - s;          // exclusive prefix
  for (int i=lo;i<hi;++i){ rowstart[i] = run; run += deg[i]; }
  if (t == 1023) rowstart[n] = part[1023];
}

// ---------------- scatter edges into CSR (by dst, stores src) ----------------
__global__ void k_fill(const int* __restrict__ ei, int E, int n,
                       const int* __restrict__ rowstart, int* __restrict__ cur, int* __restrict__ csr){
  int i = blockIdx.x*blockDim.x + threadIdx.x;
  int tot = E + n;
  if (i >= tot) return;
  int src, dst;
  if (i < E){ src = ei[i]; dst = ei[E+i]; } else { src = i - E; dst = src; }
  int pos = atomicAdd(&cur[dst], 1);
  csr[rowstart[dst] + pos] = src;
}

// ---------------- GEMM1 (bf16 MFMA): xb[M,512] @ w1t[256,512]^T -> h1b[M,256] bf16 ----
__global__ __launch_bounds__(256) void k_gemm1_mfma(const unsigned short* __restrict__ A,
                                                    const unsigned short* __restrict__ BT,
                                                    unsigned short* __restrict__ Cb, int M){
  __shared__ __align__(16) unsigned short lA[4*128*8];  // 8 KB
  __shared__ __align__(16) unsigned short lB[4*128*8];  // 8 KB
  const int t = threadIdx.x;
  const int lane = t & 63, w = t >> 6;
  const int wx = w & 1, wy = w >> 1;
  const int row0 = blockIdx.x * 128, col0 = blockIdx.y * 128;

  f32x4 acc[4][4];
  #pragma unroll
  for (int i=0;i<4;i++)
    #pragma unroll
    for (int j=0;j<4;j++)
      #pragma unroll
      for (int r=0;r<4;r++) acc[i][j][r] = 0.f;

  const int c0 = t, c1 = t + 256;
  const int r0 = c0 & 127, kq0 = c0 >> 7;
  const int r1 = c1 & 127, kq1 = c1 >> 7;
  const size_t gA0 = (size_t)min(row0 + r0, M-1)*512 + kq0*8;
  const size_t gA1 = (size_t)min(row0 + r1, M-1)*512 + kq1*8;
  const size_t gB0 = (size_t)(col0 + r0)*512 + kq0*8;
  const size_t gB1 = (size_t)(col0 + r1)*512 + kq1*8;

  const int kq = lane >> 4, li = lane & 15;

  for (int kt = 0; kt < 512; kt += 32){
    __builtin_amdgcn_global_load_lds((const __attribute__((address_space(1))) void*)(A + gA0 + kt),
        (__attribute__((address_space(3))) void*)&lA[c0*8], 16, 0, 0);
    __builtin_amdgcn_global_load_lds((const __attribute__((address_space(1))) void*)(A + gA1 + kt),
        (__attribute__((address_space(3))) void*)&lA[c1*8], 16, 0, 0);
    __builtin_amdgcn_global_load_lds((const __attribute__((address_space(1))) void*)(BT + gB0 + kt),
        (__attribute__((address_space(3))) void*)&lB[c0*8], 16, 0, 0);
    __builtin_amdgcn_global_load_lds((const __attribute__((address_space(1))) void*)(BT + gB1 + kt),
        (__attribute__((address_space(3))) void*)&lB[c1*8], 16, 0, 0);
    __syncthreads();

    bf16x8 af[4], bfr[4];
    #pragma unroll
    for (int i=0;i<4;i++){
      af[i]  = *(const bf16x8*)&lA[(kq*128 + wx*64 + i*16 + li)*8];
      bfr[i] = *(const bf16x8*)&lB[(kq*128 + wy*64 + i*16 + li)*8];
    }
    #pragma unroll
    for (int i=0;i<4;i++)
      #pragma unroll
      for (int j=0;j<4;j++)
        acc[i][j] = __builtin_amdgcn_mfma_f32_16x16x32_bf16(af[i], bfr[j], acc[i][j], 0, 0, 0);
    __syncthreads();
  }

  // epilogue: C/D map col=lane&15, row=(lane>>4)*4+reg ; store bf16
  #pragma unroll
  for (int i=0;i<4;i++){
    #pragma unroll
    for (int r=0;r<4;r++){
      int row = row0 + wx*64 + i*16 + kq*4 + r;
      if (row < M){
        #pragma unroll
        for (int j=0;j<4;j++)
          Cb[(size_t)row*256 + col0 + wy*64 + j*16 + li] = f2bf(acc[i][j][r]);
      }
    }
  }
}

// ---------------- attention coefficients L1: a_s/a_d [N,4] (bf16 h1) ----------------
__global__ __launch_bounds__(256) void k_att1(const unsigned short* __restrict__ h1b,
    const float* __restrict__ sw, const float* __restrict__ dw,
    float* __restrict__ as1, float* __restrict__ ad1, int n){
  int lane = threadIdx.x & 63;
  int node = blockIdx.x*4 + (threadIdx.x >> 6);
  if (node >= n) return;
  ushort4 hu = *(const ushort4*)(h1b + (size_t)node*256 + lane*4);
  float hx=bf2f(hu.x), hy=bf2f(hu.y), hz=bf2f(hu.z), hw=bf2f(hu.w);
  float4 sv = *(const float4*)(sw + lane*4);
  float4 dv = *(const float4*)(dw + lane*4);
  float ps = hx*sv.x + hy*sv.y + hz*sv.z + hw*sv.w;
  float pd = hx*dv.x + hy*dv.y + hz*dv.z + hw*dv.w;
  #pragma unroll
  for (int o=1;o<16;o<<=1){ ps += __shfl_xor(ps,o); pd += __shfl_xor(pd,o); }
  if ((lane & 15) == 0){
    int h = lane >> 4;
    as1[node*4+h] = ps;
    ad1[node*4+h] = pd;
  }
}

// ---------------- aggregation L1 (softmax over in-edges) + bias + ELU -> bf16 ----------
__global__ __launch_bounds__(256) void k_agg1(const unsigned short* __restrict__ h1b,
    const float* __restrict__ as1, const float* __restrict__ ad1,
    const int* __restrict__ rowstart, const int* __restrict__ csr,
    const float* __restrict__ b1, unsigned short* __restrict__ hactb, int n){
  int lane = threadIdx.x & 63;
  int node = blockIdx.x*4 + (threadIdx.x >> 6);
  if (node >= n) return;
  int lo = rowstart[node], hi = rowstart[node+1];
  float4 adv = *(const float4*)(ad1 + node*4);
  float m0=-INFINITY, m1=-INFINITY, m2=-INFINITY, m3=-INFINITY;
  for (int e = lo + lane; e < hi; e += 64){
    int s = csr[e];
    float4 asv = *(const float4*)(as1 + s*4);
    m0 = fmaxf(m0, leaky(asv.x + adv.x));
    m1 = fmaxf(m1, leaky(asv.y + adv.y));
    m2 = fmaxf(m2, leaky(asv.z + adv.z));
    m3 = fmaxf(m3, leaky(asv.w + adv.w));
  }
  #pragma unroll
  for (int o=1;o<64;o<<=1){
    m0 = fmaxf(m0, __shfl_xor(m0,o));
    m1 = fmaxf(m1, __shfl_xor(m1,o));
    m2 = fmaxf(m2, __shfl_xor(m2,o));
    m3 = fmaxf(m3, __shfl_xor(m3,o));
  }
  int h = lane >> 4;                         // head of this lane's 4 channels
  float mh  = (h==0)?m0:(h==1)?m1:(h==2)?m2:m3;
  float adh = (h==0)?adv.x:(h==1)?adv.y:(h==2)?adv.z:adv.w;
  float ax=0.f, ay=0.f, az=0.f, aw=0.f, ssum=0.f;
  int e = lo;
  for (; e + 1 < hi; e += 2){                // 2-edge unroll: 2x loads in flight
    int s0 = csr[e], s1 = csr[e+1];
    float x0 = __expf(leaky(as1[s0*4+h] + adh) - mh);
    float x1 = __expf(leaky(as1[s1*4+h] + adh) - mh);
    ushort4 u0 = *(const ushort4*)(h1b + (size_t)s0*256 + lane*4);
    ushort4 u1 = *(const ushort4*)(h1b + (size_t)s1*256 + lane*4);
    ax += x0*bf2f(u0.x) + x1*bf2f(u1.x);
    ay += x0*bf2f(u0.y) + x1*bf2f(u1.y);
    az += x0*bf2f(u0.z) + x1*bf2f(u1.z);
    aw += x0*bf2f(u0.w) + x1*bf2f(u1.w);
    ssum += x0 + x1;
  }
  if (e < hi){
    int s0 = csr[e];
    float x0 = __expf(leaky(as1[s0*4+h] + adh) - mh);
    ushort4 u0 = *(const ushort4*)(h1b + (size_t)s0*256 + lane*4);
    ax += x0*bf2f(u0.x); ay += x0*bf2f(u0.y); az += x0*bf2f(u0.z); aw += x0*bf2f(u0.w);
    ssum += x0;
  }
  float inv = 1.f/(ssum + 1e-16f);
  float4 bv = *(const float4*)(b1 + lane*4);
  float o0 = ax*inv + bv.x, o1 = ay*inv + bv.y, o2 = az*inv + bv.z, o3 = aw*inv + bv.w;
  ushort4 r;
  r.x = f2bf(o0 > 0.f ? o0 : expm1f(o0));
  r.y = f2bf(o1 > 0.f ? o1 : expm1f(o1));
  r.z = f2bf(o2 > 0.f ? o2 : expm1f(o2));
  r.w = f2bf(o3 > 0.f ? o3 : expm1f(o3));
  *(ushort4*)(hactb + (size_t)node*256 + lane*4) = r;
}

// ---------------- GEMM2: hact[M,256]bf16 @ W2[256,40]f32 -> h2b[M,40]bf16 ------------
// + fused att2: as2/ad2 [N] via LDS reduce.
__global__ __launch_bounds__(256) void k_gemm2(const unsigned short* __restrict__ A,
    const float* __restrict__ B, const float* __restrict__ sw, const float* __restrict__ dw,
    unsigned short* __restrict__ Cb, float* __restrict__ as2, float* __restrict__ ad2, int M){
  __shared__ float Xl[32][129];       // pad -> conflict-free column reads
  __shared__ float Wl[128*40];
  __shared__ float Sps[32][8], Spd[32][8];
  int t = threadIdx.x;
  int row0 = blockIdx.x*32;
  int r = t & 31, g = t >> 5;         // g in 0..7 -> cols g*5 .. g*5+4
  float acc[5] = {0,0,0,0,0};
  for (int kt=0; kt<256; kt+=128){
    for (int i=t; i<1280; i+=256)
      *(float4*)&Wl[i*4] = *(const float4*)(B + kt*40 + i*4);
    for (int i=t; i<512; i+=256){     // 32 rows x 128 k, 8 bf16 per chunk
      int rr = i >> 4, k8 = i & 15;
      int grow = row0 + rr; if (grow >= M) grow = M-1;
      uint4 v = *(const uint4*)(A + (size_t)grow*256 + kt + k8*8);
      float* xp = &Xl[rr][k8*8];
      xp[0] = __uint_as_float(v.x << 16); xp[1] = __uint_as_float(v.x & 0xffff0000u);
      xp[2] = __uint_as_float(v.y << 16); xp[3] = __uint_as_float(v.y & 0xffff0000u);
      xp[4] = __uint_as_float(v.z << 16); xp[5] = __uint_as_float(v.z & 0xffff0000u);
      xp[6] = __uint_as_float(v.w << 16); xp[7] = __uint_as_float(v.w & 0xffff0000u);
    }
    __syncthreads();
    #pragma unroll 4
    for (int k=0;k<128;++k){
      float a = Xl[r][k];
      const float* wp = &Wl[k*40 + g*5];
      #pragma unroll
      for (int j=0;j<5;++j) acc[j] += a * wp[j];
    }
    __syncthreads();
  }
  int grow = row0 + r;
  float ps = 0.f, pd = 0.f;
  #pragma unroll
  for (int j=0;j<5;++j){
    ps += acc[j] * sw[g*5+j];
    pd += acc[j] * dw[g*5+j];
  }
  Sps[r][g] = ps; Spd[r][g] = pd;
  if (grow < M){
    #pragma unroll
    for (int j=0;j<5;++j) Cb[(size_t)grow*40 + g*5 + j] = f2bf(acc[j]);
  }
  __syncthreads();
  if (t < 32){
    float a = 0.f, b = 0.f;
    #pragma unroll
    for (int g2=0; g2<8; ++g2){ a += Sps[t][g2]; b += Spd[t][g2]; }
    int rw = row0 + t;
    if (rw < M){ as2[rw] = a; ad2[rw] = b; }
  }
}

// ---------------- aggregation L2 + bias + log_softmax -> out ----------------
__global__ __launch_bounds__(256) void k_agg2(const unsigned short* __restrict__ h2b,
    const float* __restrict__ as2, const float* __restrict__ ad2,
    const int* __restrict__ rowstart, const int* __restrict__ csr,
    const float* __restrict__ b2, float* __restrict__ out, int n){
  int lane = threadIdx.x & 63;
  int node = blockIdx.x*4 + (threadIdx.x >> 6);
  if (node >= n) return;
  int lo = rowstart[node], hi = rowstart[node+1];
  float adn = ad2[node];
  float m = -INFINITY;
  for (int e = lo + lane; e < hi; e += 64){
    int s = csr[e];
    m = fmaxf(m, leaky(as2[s] + adn));
  }
  #pragma unroll
  for (int o=1;o<64;o<<=1) m = fmaxf(m, __shfl_xor(m,o));
  bool act = lane < 40;
  float acc = 0.f, ssum = 0.f;
  for (int e = lo; e < hi; ++e){
    int s = csr[e];
    float ex = __expf(leaky(as2[s] + adn) - m);
    ssum += ex;
    float hv = act ? bf2f(h2b[(size_t)s*40 + lane]) : 0.f;
    acc += ex*hv;
  }
  float ov = acc/(ssum + 1e-16f) + (act ? b2[lane] : 0.f);
  float v = act ? ov : -INFINITY;
  float mx = v;
  #pragma unroll
  for (int o=1;o<64;o<<=1) mx = fmaxf(mx, __shfl_xor(mx,o));
  float ev = act ? __expf(ov - mx) : 0.f;
  float se = ev;
  #pragma unroll
  for (int o=1;o<64;o<<=1) se += __shfl_xor(se,o);
  if (act) out[(size_t)node*40 + lane] = (ov - mx) - __logf(se);
}

extern "C" void kernel_launch(void* const* d_in, const int* in_sizes, int n_in,
                              void* d_out, int out_size, void* d_ws, size_t ws_size,
                              hipStream_t stream){
  const float* x   = (const float*)d_in[0];
  const int*   ei  = (const int*)d_in[1];     // [2,E] int32 (harness contract)
  const float* W1  = (const float*)d_in[2];
  const float* s1w = (const float*)d_in[3];
  const float* d1w = (const float*)d_in[4];
  const float* b1  = (const float*)d_in[5];
  const float* W2  = (const float*)d_in[6];
  const float* s2w = (const float*)d_in[7];
  const float* d2w = (const float*)d_in[8];
  const float* b2  = (const float*)d_in[9];
  float* out = (float*)d_out;

  const int N  = in_sizes[0] / 512;
  const int E  = in_sizes[1] / 2;
  const int Et = E + N;

  // workspace carve-out (~110 MB)
  float* f = (float*)d_ws;
  unsigned short* h1b   = (unsigned short*)f;  f += (size_t)N*128;   // [N][256] bf16
  unsigned short* hactb = (unsigned short*)f;  f += (size_t)N*128;   // [N][256] bf16
  float* as1  = f;  f += (size_t)N*4;
  float* ad1  = f;  f += (size_t)N*4;
  float* as2  = f;  f += N;
  float* ad2  = f;  f += N;
  unsigned short* w1t = (unsigned short*)f;  f += 256*512/2;         // [256][512] bf16
  unsigned short* xb  = (unsigned short*)f;  f += (size_t)N*256;     // [N][512] bf16
  unsigned short* h2b = xb;                  // alias: xb dead after gemm1
  int* ip = (int*)f;
  int* rowstart = ip;  ip += (N + 4) & ~3;
  int* deg      = ip;  ip += N;              // deg+cur adjacent -> single memset
  int* cur      = ip;  ip += N;
  int* csr      = ip;  ip += Et;

  int nb4 = (N + 3) / 4;
  int n4  = (N*512)/4;
  k_cvt_x<<<(n4+255)/256, 256, 0, stream>>>(x, xb, n4);
  k_cvt_w<<<512, 256, 0, stream>>>(W1, w1t);
  hipMemsetAsync(deg, 0, (size_t)2*N*sizeof(int), stream);
  k_count<<<(Et+255)/256, 256, 0, stream>>>(ei, E, N, deg);
  k_scan <<<1, 1024, 0, stream>>>(deg, rowstart, N);
  k_fill <<<(Et+255)/256, 256, 0, stream>>>(ei, E, N, rowstart, cur, csr);
  k_gemm1_mfma<<<dim3((N+127)/128, 2), 256, 0, stream>>>(xb, w1t, h1b, N);
  k_att1 <<<nb4, 256, 0, stream>>>(h1b, s1w, d1w, as1, ad1, N);
  k_agg1 <<<nb4, 256, 0, stream>>>(h1b, as1, ad1, rowstart, csr, b1, hactb, N);
  k_gemm2<<<(N+31)/32, 256, 0, stream>>>(hactb, W2, s2w, d2w, h2b, as2, ad2, N);
  k_agg2 <<<nb4, 256, 0, stream>>>(h2b, as2, ad2, rowstart, csr, b2, out, N);
}

// Round 4
// 553.925 us; speedup vs baseline: 1.3946x; 1.0646x over previous
//
#include <hip/hip_runtime.h>
#include <math.h>
#include <stdint.h>

// GAT 2-layer: N=50000 nodes, E=800000 edges (+N self loops)
// L1: 512 -> 4 heads x 64 (bf16 MFMA GEMM), ELU.  L2: 256 -> 1 head x 40, log_softmax.
// All intermediate node features (h1, hact, h2) stored bf16; accumulation fp32.

typedef short bf16x8 __attribute__((ext_vector_type(8)));
typedef float f32x4  __attribute__((ext_vector_type(4)));

static __device__ __forceinline__ float leaky(float x){ return x > 0.f ? x : 0.2f*x; }
static __device__ __forceinline__ unsigned short f2bf(float f){
  uint32_t u = __float_as_uint(f);
  uint32_t r = u + 0x7fffu + ((u >> 16) & 1u);   // RNE
  return (unsigned short)(r >> 16);
}
static __device__ __forceinline__ float bf2f(unsigned short u){
  return __uint_as_float(((uint32_t)u) << 16);
}

// ---------------- convert x -> bf16 (vectorized) ----------------
__global__ void k_cvt_x(const float* __restrict__ x, unsigned short* __restrict__ xb, int n4){
  int i = blockIdx.x*blockDim.x + threadIdx.x;
  if (i >= n4) return;
  float4 v = ((const float4*)x)[i];
  ushort4 o; o.x=f2bf(v.x); o.y=f2bf(v.y); o.z=f2bf(v.z); o.w=f2bf(v.w);
  ((ushort4*)xb)[i] = o;
}

// ---------------- convert+transpose W1[512][256] -> w1t[256][512] bf16 ----------------
__global__ void k_cvt_w(const float* __restrict__ W, unsigned short* __restrict__ wt){
  int i = blockIdx.x*blockDim.x + threadIdx.x;   // 0..131071
  if (i >= 512*256) return;
  int k = i >> 8, n = i & 255;
  wt[n*512 + k] = f2bf(W[i]);
}

// ---------------- count in-degree (incl self loops) ----------------
__global__ void k_count(const int* __restrict__ ei, int E, int n, int* __restrict__ deg){
  int i = blockIdx.x*blockDim.x + threadIdx.x;
  int tot = E + n;
  if (i >= tot) return;
  int dst = (i < E) ? ei[E + i] : (i - E);
  atomicAdd(&deg[dst], 1);
}

// ---------------- exclusive scan -> rowstart[0..n] ----------------
__global__ __launch_bounds__(1024) void k_scan(const int* __restrict__ deg, int* __restrict__ rowstart, int n){
  __shared__ int part[1024];
  int t = threadIdx.x;
  int chunk = (n + 1023) >> 10;
  int lo = t*chunk, hi = lo + chunk;
  if (lo > n) lo = n;
  if (hi > n) hi = n;
  int s = 0;
  for (int i=lo;i<hi;++i) s += deg[i];
  part[t] = s;
  __syncthreads();
  for (int off=1; off<1024; off<<=1){
    int v = (t >= off) ? part[t-off] : 0;
    __syncthreads();
    part[t] += v;
    __syncthreads();
  }
  int run = part[t] - s;          // exclusive prefix
  for (int i=lo;i<hi;++i){ rowstart[i] = run; run += deg[i]; }
  if (t == 1023) rowstart[n] = part[1023];
}

// ---------------- scatter edges into CSR (by dst, stores src) ----------------
__global__ void k_fill(const int* __restrict__ ei, int E, int n,
                       const int* __restrict__ rowstart, int* __restrict__ cur, int* __restrict__ csr){
  int i = blockIdx.x*blockDim.x + threadIdx.x;
  int tot = E + n;
  if (i >= tot) return;
  int src, dst;
  if (i < E){ src = ei[i]; dst = ei[E+i]; } else { src = i - E; dst = src; }
  int pos = atomicAdd(&cur[dst], 1);
  csr[rowstart[dst] + pos] = src;
}

// ---------------- GEMM1 (bf16 MFMA): xb[M,512] @ w1t[256,512]^T -> h1b[M,256] bf16 ----
__global__ __launch_bounds__(256) void k_gemm1_mfma(const unsigned short* __restrict__ A,
                                                    const unsigned short* __restrict__ BT,
                                                    unsigned short* __restrict__ Cb, int M){
  __shared__ __align__(16) unsigned short lA[4*128*8];  // 8 KB
  __shared__ __align__(16) unsigned short lB[4*128*8];  // 8 KB
  const int t = threadIdx.x;
  const int lane = t & 63, w = t >> 6;
  const int wx = w & 1, wy = w >> 1;
  const int row0 = blockIdx.x * 128, col0 = blockIdx.y * 128;

  f32x4 acc[4][4];
  #pragma unroll
  for (int i=0;i<4;i++)
    #pragma unroll
    for (int j=0;j<4;j++)
      #pragma unroll
      for (int r=0;r<4;r++) acc[i][j][r] = 0.f;

  const int c0 = t, c1 = t + 256;
  const int r0 = c0 & 127, kq0 = c0 >> 7;
  const int r1 = c1 & 127, kq1 = c1 >> 7;
  const size_t gA0 = (size_t)min(row0 + r0, M-1)*512 + kq0*8;
  const size_t gA1 = (size_t)min(row0 + r1, M-1)*512 + kq1*8;
  const size_t gB0 = (size_t)(col0 + r0)*512 + kq0*8;
  const size_t gB1 = (size_t)(col0 + r1)*512 + kq1*8;

  const int kq = lane >> 4, li = lane & 15;

  for (int kt = 0; kt < 512; kt += 32){
    __builtin_amdgcn_global_load_lds((const __attribute__((address_space(1))) void*)(A + gA0 + kt),
        (__attribute__((address_space(3))) void*)&lA[c0*8], 16, 0, 0);
    __builtin_amdgcn_global_load_lds((const __attribute__((address_space(1))) void*)(A + gA1 + kt),
        (__attribute__((address_space(3))) void*)&lA[c1*8], 16, 0, 0);
    __builtin_amdgcn_global_load_lds((const __attribute__((address_space(1))) void*)(BT + gB0 + kt),
        (__attribute__((address_space(3))) void*)&lB[c0*8], 16, 0, 0);
    __builtin_amdgcn_global_load_lds((const __attribute__((address_space(1))) void*)(BT + gB1 + kt),
        (__attribute__((address_space(3))) void*)&lB[c1*8], 16, 0, 0);
    __syncthreads();

    bf16x8 af[4], bfr[4];
    #pragma unroll
    for (int i=0;i<4;i++){
      af[i]  = *(const bf16x8*)&lA[(kq*128 + wx*64 + i*16 + li)*8];
      bfr[i] = *(const bf16x8*)&lB[(kq*128 + wy*64 + i*16 + li)*8];
    }
    #pragma unroll
    for (int i=0;i<4;i++)
      #pragma unroll
      for (int j=0;j<4;j++)
        acc[i][j] = __builtin_amdgcn_mfma_f32_16x16x32_bf16(af[i], bfr[j], acc[i][j], 0, 0, 0);
    __syncthreads();
  }

  // epilogue: C/D map col=lane&15, row=(lane>>4)*4+reg ; store bf16
  #pragma unroll
  for (int i=0;i<4;i++){
    #pragma unroll
    for (int r=0;r<4;r++){
      int row = row0 + wx*64 + i*16 + kq*4 + r;
      if (row < M){
        #pragma unroll
        for (int j=0;j<4;j++)
          Cb[(size_t)row*256 + col0 + wy*64 + j*16 + li] = f2bf(acc[i][j][r]);
      }
    }
  }
}

// ---------------- attention coefficients L1: a_s/a_d [N,4] (bf16 h1) ----------------
__global__ __launch_bounds__(256) void k_att1(const unsigned short* __restrict__ h1b,
    const float* __restrict__ sw, const float* __restrict__ dw,
    float* __restrict__ as1, float* __restrict__ ad1, int n){
  int lane = threadIdx.x & 63;
  int node = blockIdx.x*4 + (threadIdx.x >> 6);
  if (node >= n) return;
  ushort4 hu = *(const ushort4*)(h1b + (size_t)node*256 + lane*4);
  float hx=bf2f(hu.x), hy=bf2f(hu.y), hz=bf2f(hu.z), hw=bf2f(hu.w);
  float4 sv = *(const float4*)(sw + lane*4);
  float4 dv = *(const float4*)(dw + lane*4);
  float ps = hx*sv.x + hy*sv.y + hz*sv.z + hw*sv.w;
  float pd = hx*dv.x + hy*dv.y + hz*dv.z + hw*dv.w;
  #pragma unroll
  for (int o=1;o<16;o<<=1){ ps += __shfl_xor(ps,o); pd += __shfl_xor(pd,o); }
  if ((lane & 15) == 0){
    int h = lane >> 4;
    as1[node*4+h] = ps;
    ad1[node*4+h] = pd;
  }
}

// ---------------- aggregation L1 (softmax over in-edges) + bias + ELU -> bf16 ----------
__global__ __launch_bounds__(256) void k_agg1(const unsigned short* __restrict__ h1b,
    const float* __restrict__ as1, const float* __restrict__ ad1,
    const int* __restrict__ rowstart, const int* __restrict__ csr,
    const float* __restrict__ b1, unsigned short* __restrict__ hactb, int n){
  int lane = threadIdx.x & 63;
  int node = blockIdx.x*4 + (threadIdx.x >> 6);
  if (node >= n) return;
  int lo = rowstart[node], hi = rowstart[node+1];
  float4 adv = *(const float4*)(ad1 + node*4);
  float m0=-INFINITY, m1=-INFINITY, m2=-INFINITY, m3=-INFINITY;
  for (int e = lo + lane; e < hi; e += 64){
    int s = csr[e];
    float4 asv = *(const float4*)(as1 + s*4);
    m0 = fmaxf(m0, leaky(asv.x + adv.x));
    m1 = fmaxf(m1, leaky(asv.y + adv.y));
    m2 = fmaxf(m2, leaky(asv.z + adv.z));
    m3 = fmaxf(m3, leaky(asv.w + adv.w));
  }
  #pragma unroll
  for (int o=1;o<64;o<<=1){
    m0 = fmaxf(m0, __shfl_xor(m0,o));
    m1 = fmaxf(m1, __shfl_xor(m1,o));
    m2 = fmaxf(m2, __shfl_xor(m2,o));
    m3 = fmaxf(m3, __shfl_xor(m3,o));
  }
  int h = lane >> 4;                         // head of this lane's 4 channels
  float mh  = (h==0)?m0:(h==1)?m1:(h==2)?m2:m3;
  float adh = (h==0)?adv.x:(h==1)?adv.y:(h==2)?adv.z:adv.w;
  float ax=0.f, ay=0.f, az=0.f, aw=0.f, ssum=0.f;
  int e = lo;
  for (; e + 3 < hi; e += 4){                // 4-edge unroll: 4x gathers in flight
    int s0 = csr[e], s1 = csr[e+1], s2 = csr[e+2], s3 = csr[e+3];
    float x0 = __expf(leaky(as1[s0*4+h] + adh) - mh);
    float x1 = __expf(leaky(as1[s1*4+h] + adh) - mh);
    float x2 = __expf(leaky(as1[s2*4+h] + adh) - mh);
    float x3 = __expf(leaky(as1[s3*4+h] + adh) - mh);
    ushort4 u0 = *(const ushort4*)(h1b + (size_t)s0*256 + lane*4);
    ushort4 u1 = *(const ushort4*)(h1b + (size_t)s1*256 + lane*4);
    ushort4 u2 = *(const ushort4*)(h1b + (size_t)s2*256 + lane*4);
    ushort4 u3 = *(const ushort4*)(h1b + (size_t)s3*256 + lane*4);
    ax += x0*bf2f(u0.x) + x1*bf2f(u1.x) + x2*bf2f(u2.x) + x3*bf2f(u3.x);
    ay += x0*bf2f(u0.y) + x1*bf2f(u1.y) + x2*bf2f(u2.y) + x3*bf2f(u3.y);
    az += x0*bf2f(u0.z) + x1*bf2f(u1.z) + x2*bf2f(u2.z) + x3*bf2f(u3.z);
    aw += x0*bf2f(u0.w) + x1*bf2f(u1.w) + x2*bf2f(u2.w) + x3*bf2f(u3.w);
    ssum += x0 + x1 + x2 + x3;
  }
  for (; e < hi; ++e){
    int s0 = csr[e];
    float x0 = __expf(leaky(as1[s0*4+h] + adh) - mh);
    ushort4 u0 = *(const ushort4*)(h1b + (size_t)s0*256 + lane*4);
    ax += x0*bf2f(u0.x); ay += x0*bf2f(u0.y); az += x0*bf2f(u0.z); aw += x0*bf2f(u0.w);
    ssum += x0;
  }
  float inv = 1.f/(ssum + 1e-16f);
  float4 bv = *(const float4*)(b1 + lane*4);
  float o0 = ax*inv + bv.x, o1 = ay*inv + bv.y, o2 = az*inv + bv.z, o3 = aw*inv + bv.w;
  ushort4 r;
  r.x = f2bf(o0 > 0.f ? o0 : expm1f(o0));
  r.y = f2bf(o1 > 0.f ? o1 : expm1f(o1));
  r.z = f2bf(o2 > 0.f ? o2 : expm1f(o2));
  r.w = f2bf(o3 > 0.f ? o3 : expm1f(o3));
  *(ushort4*)(hactb + (size_t)node*256 + lane*4) = r;
}

// ---------------- GEMM2: hact[M,256]bf16 @ W2[256,40]f32 -> h2b[M,40]bf16 ------------
// + fused att2: as2/ad2 [N] via LDS reduce.
__global__ __launch_bounds__(256) void k_gemm2(const unsigned short* __restrict__ A,
    const float* __restrict__ B, const float* __restrict__ sw, const float* __restrict__ dw,
    unsigned short* __restrict__ Cb, float* __restrict__ as2, float* __restrict__ ad2, int M){
  __shared__ float Xl[32][129];       // pad -> conflict-free column reads
  __shared__ float Wl[128*40];
  __shared__ float Sps[32][8], Spd[32][8];
  int t = threadIdx.x;
  int row0 = blockIdx.x*32;
  int r = t & 31, g = t >> 5;         // g in 0..7 -> cols g*5 .. g*5+4
  float acc[5] = {0,0,0,0,0};
  for (int kt=0; kt<256; kt+=128){
    for (int i=t; i<1280; i+=256)
      *(float4*)&Wl[i*4] = *(const float4*)(B + kt*40 + i*4);
    for (int i=t; i<512; i+=256){     // 32 rows x 128 k, 8 bf16 per chunk
      int rr = i >> 4, k8 = i & 15;
      int grow = row0 + rr; if (grow >= M) grow = M-1;
      uint4 v = *(const uint4*)(A + (size_t)grow*256 + kt + k8*8);
      float* xp = &Xl[rr][k8*8];
      xp[0] = __uint_as_float(v.x << 16); xp[1] = __uint_as_float(v.x & 0xffff0000u);
      xp[2] = __uint_as_float(v.y << 16); xp[3] = __uint_as_float(v.y & 0xffff0000u);
      xp[4] = __uint_as_float(v.z << 16); xp[5] = __uint_as_float(v.z & 0xffff0000u);
      xp[6] = __uint_as_float(v.w << 16); xp[7] = __uint_as_float(v.w & 0xffff0000u);
    }
    __syncthreads();
    #pragma unroll 4
    for (int k=0;k<128;++k){
      float a = Xl[r][k];
      const float* wp = &Wl[k*40 + g*5];
      #pragma unroll
      for (int j=0;j<5;++j) acc[j] += a * wp[j];
    }
    __syncthreads();
  }
  int grow = row0 + r;
  float ps = 0.f, pd = 0.f;
  #pragma unroll
  for (int j=0;j<5;++j){
    ps += acc[j] * sw[g*5+j];
    pd += acc[j] * dw[g*5+j];
  }
  Sps[r][g] = ps; Spd[r][g] = pd;
  if (grow < M){
    #pragma unroll
    for (int j=0;j<5;++j) Cb[(size_t)grow*40 + g*5 + j] = f2bf(acc[j]);
  }
  __syncthreads();
  if (t < 32){
    float a = 0.f, b = 0.f;
    #pragma unroll
    for (int g2=0; g2<8; ++g2){ a += Sps[t][g2]; b += Spd[t][g2]; }
    int rw = row0 + t;
    if (rw < M){ as2[rw] = a; ad2[rw] = b; }
  }
}

// ---------------- aggregation L2 + bias + log_softmax -> out ----------------
// Chunk-broadcast: logits/exp computed lane-parallel, gather loop unrolled x4.
__global__ __launch_bounds__(256) void k_agg2(const unsigned short* __restrict__ h2b,
    const float* __restrict__ as2, const float* __restrict__ ad2,
    const int* __restrict__ rowstart, const int* __restrict__ csr,
    const float* __restrict__ b2, float* __restrict__ out, int n){
  int lane = threadIdx.x & 63;
  int node = blockIdx.x*4 + (threadIdx.x >> 6);
  if (node >= n) return;
  int lo = rowstart[node], hi = rowstart[node+1];
  int deg = hi - lo;
  float adn = ad2[node];
  // pass 1: lane-parallel logits; cache first chunk's (src, logit) in regs
  int   sl = 0;
  float ll = -INFINITY;
  if (lane < deg){ sl = csr[lo + lane]; ll = leaky(as2[sl] + adn); }
  float m = ll;
  for (int e = lo + lane + 64; e < hi; e += 64)
    m = fmaxf(m, leaky(as2[csr[e]] + adn));
  #pragma unroll
  for (int o=1;o<64;o<<=1) m = fmaxf(m, __shfl_xor(m,o));

  bool act = lane < 40;
  float acc = 0.f, psum = 0.f;
  for (int c = lo; c < hi; c += 64){
    int cnt = min(64, hi - c);
    int   s_l; float ex_l;
    if (c == lo){
      s_l = sl; ex_l = (lane < cnt) ? __expf(ll - m) : 0.f;
    } else {
      s_l = 0; ex_l = 0.f;
      if (lane < cnt){ s_l = csr[c + lane]; ex_l = __expf(leaky(as2[s_l] + adn) - m); }
    }
    psum += ex_l;
    int j = 0;
    for (; j + 3 < cnt; j += 4){
      int   s0=__shfl(s_l,j),  s1=__shfl(s_l,j+1),  s2=__shfl(s_l,j+2),  s3=__shfl(s_l,j+3);
      float e0=__shfl(ex_l,j), e1=__shfl(ex_l,j+1), e2=__shfl(ex_l,j+2), e3=__shfl(ex_l,j+3);
      float h0 = act ? bf2f(h2b[(size_t)s0*40 + lane]) : 0.f;
      float h1 = act ? bf2f(h2b[(size_t)s1*40 + lane]) : 0.f;
      float h2 = act ? bf2f(h2b[(size_t)s2*40 + lane]) : 0.f;
      float h3 = act ? bf2f(h2b[(size_t)s3*40 + lane]) : 0.f;
      acc += e0*h0; acc += e1*h1; acc += e2*h2; acc += e3*h3;
    }
    for (; j < cnt; ++j){
      int s0=__shfl(s_l,j); float e0=__shfl(ex_l,j);
      acc += e0 * (act ? bf2f(h2b[(size_t)s0*40 + lane]) : 0.f);
    }
  }
  float ssum = psum;
  #pragma unroll
  for (int o=1;o<64;o<<=1) ssum += __shfl_xor(ssum,o);
  float ov = acc/(ssum + 1e-16f) + (act ? b2[lane] : 0.f);
  float v = act ? ov : -INFINITY;
  float mx = v;
  #pragma unroll
  for (int o=1;o<64;o<<=1) mx = fmaxf(mx, __shfl_xor(mx,o));
  float ev = act ? __expf(ov - mx) : 0.f;
  float se = ev;
  #pragma unroll
  for (int o=1;o<64;o<<=1) se += __shfl_xor(se,o);
  if (act) out[(size_t)node*40 + lane] = (ov - mx) - __logf(se);
}

extern "C" void kernel_launch(void* const* d_in, const int* in_sizes, int n_in,
                              void* d_out, int out_size, void* d_ws, size_t ws_size,
                              hipStream_t stream){
  const float* x   = (const float*)d_in[0];
  const int*   ei  = (const int*)d_in[1];     // [2,E] int32 (harness contract)
  const float* W1  = (const float*)d_in[2];
  const float* s1w = (const float*)d_in[3];
  const float* d1w = (const float*)d_in[4];
  const float* b1  = (const float*)d_in[5];
  const float* W2  = (const float*)d_in[6];
  const float* s2w = (const float*)d_in[7];
  const float* d2w = (const float*)d_in[8];
  const float* b2  = (const float*)d_in[9];
  float* out = (float*)d_out;

  const int N  = in_sizes[0] / 512;
  const int E  = in_sizes[1] / 2;
  const int Et = E + N;

  // workspace carve-out (~110 MB)
  float* f = (float*)d_ws;
  unsigned short* h1b   = (unsigned short*)f;  f += (size_t)N*128;   // [N][256] bf16
  unsigned short* hactb = (unsigned short*)f;  f += (size_t)N*128;   // [N][256] bf16
  float* as1  = f;  f += (size_t)N*4;
  float* ad1  = f;  f += (size_t)N*4;
  float* as2  = f;  f += N;
  float* ad2  = f;  f += N;
  unsigned short* w1t = (unsigned short*)f;  f += 256*512/2;         // [256][512] bf16
  unsigned short* xb  = (unsigned short*)f;  f += (size_t)N*256;     // [N][512] bf16
  unsigned short* h2b = xb;                  // alias: xb dead after gemm1
  int* ip = (int*)f;
  int* rowstart = ip;  ip += (N + 4) & ~3;
  int* deg      = ip;  ip += N;              // deg+cur adjacent -> single memset
  int* cur      = ip;  ip += N;
  int* csr      = ip;  ip += Et;

  int nb4 = (N + 3) / 4;
  int n4  = (N*512)/4;
  k_cvt_x<<<(n4+255)/256, 256, 0, stream>>>(x, xb, n4);
  k_cvt_w<<<512, 256, 0, stream>>>(W1, w1t);
  hipMemsetAsync(deg, 0, (size_t)2*N*sizeof(int), stream);
  k_count<<<(Et+255)/256, 256, 0, stream>>>(ei, E, N, deg);
  k_scan <<<1, 1024, 0, stream>>>(deg, rowstart, N);
  k_fill <<<(Et+255)/256, 256, 0, stream>>>(ei, E, N, rowstart, cur, csr);
  k_gemm1_mfma<<<dim3((N+127)/128, 2), 256, 0, stream>>>(xb, w1t, h1b, N);
  k_att1 <<<nb4, 256, 0, stream>>>(h1b, s1w, d1w, as1, ad1, N);
  k_agg1 <<<nb4, 256, 0, stream>>>(h1b, as1, ad1, rowstart, csr, b1, hactb, N);
  k_gemm2<<<(N+31)/32, 256, 0, stream>>>(hactb, W2, s2w, d2w, h2b, as2, ad2, N);
  k_agg2 <<<nb4, 256, 0, stream>>>(h2b, as2, ad2, rowstart, csr, b2, out, N);
}

// Round 5
// 488.204 us; speedup vs baseline: 1.5823x; 1.1346x over previous
//
#include <hip/hip_runtime.h>
#include <math.h>
#include <stdint.h>

// GAT 2-layer: N=50000 nodes, E=800000 edges (+N self loops)
// L1: 512 -> 4 heads x 64 (bf16 MFMA GEMM), ELU.  L2: 256 -> 1 head x 40, log_softmax.
// All intermediate node features (h1, hact, h2) stored bf16; accumulation fp32.

typedef short bf16x8 __attribute__((ext_vector_type(8)));
typedef float f32x4  __attribute__((ext_vector_type(4)));

static __device__ __forceinline__ float leaky(float x){ return x > 0.f ? x : 0.2f*x; }
static __device__ __forceinline__ unsigned short f2bf(float f){
  uint32_t u = __float_as_uint(f);
  uint32_t r = u + 0x7fffu + ((u >> 16) & 1u);   // RNE
  return (unsigned short)(r >> 16);
}
static __device__ __forceinline__ float bf2f(unsigned short u){
  return __uint_as_float(((uint32_t)u) << 16);
}

// ---------------- convert x -> bf16 (vectorized) ----------------
__global__ void k_cvt_x(const float* __restrict__ x, unsigned short* __restrict__ xb, int n4){
  int i = blockIdx.x*blockDim.x + threadIdx.x;
  if (i >= n4) return;
  float4 v = ((const float4*)x)[i];
  ushort4 o; o.x=f2bf(v.x); o.y=f2bf(v.y); o.z=f2bf(v.z); o.w=f2bf(v.w);
  ((ushort4*)xb)[i] = o;
}

// ---------------- convert+transpose W1[512][256] -> w1t[256][512] bf16 ----------------
__global__ void k_cvt_w(const float* __restrict__ W, unsigned short* __restrict__ wt){
  int i = blockIdx.x*blockDim.x + threadIdx.x;   // 0..131071
  if (i >= 512*256) return;
  int k = i >> 8, n = i & 255;
  wt[n*512 + k] = f2bf(W[i]);
}

// ---------------- count in-degree (incl self loops) ----------------
__global__ void k_count(const int* __restrict__ ei, int E, int n, int* __restrict__ deg){
  int i = blockIdx.x*blockDim.x + threadIdx.x;
  int tot = E + n;
  if (i >= tot) return;
  int dst = (i < E) ? ei[E + i] : (i - E);
  atomicAdd(&deg[dst], 1);
}

// ---------------- multi-block exclusive scan: deg[n] -> rowstart[0..n] ----------------
// Phase A: per-block inclusive scan of 256-elem chunk -> rowstart[i+1], block total -> bsum[b]
__global__ __launch_bounds__(256) void k_scan_a(const int* __restrict__ deg,
    int* __restrict__ rowstart, int* __restrict__ bsum, int n){
  __shared__ int sm[256];
  int b = blockIdx.x, t = threadIdx.x;
  int i = b*256 + t;
  int v = (i < n) ? deg[i] : 0;
  sm[t] = v;
  __syncthreads();
  for (int off=1; off<256; off<<=1){
    int u = (t >= off) ? sm[t-off] : 0;
    __syncthreads();
    sm[t] += u;
    __syncthreads();
  }
  if (i < n) rowstart[i+1] = sm[t];
  if (t == 255) bsum[b] = sm[255];
}
// Phase B: one block exclusive-scans bsum[nb] in place (nb <= 256)
__global__ __launch_bounds__(256) void k_scan_b(int* __restrict__ bsum, int nb){
  __shared__ int sm[256];
  int t = threadIdx.x;
  int v = (t < nb) ? bsum[t] : 0;
  sm[t] = v;
  __syncthreads();
  for (int off=1; off<256; off<<=1){
    int u = (t >= off) ? sm[t-off] : 0;
    __syncthreads();
    sm[t] += u;
    __syncthreads();
  }
  if (t < nb) bsum[t] = sm[t] - v;   // exclusive prefix
}
// Phase C: add block offsets; rowstart[0] = 0
__global__ __launch_bounds__(256) void k_scan_c(int* __restrict__ rowstart,
    const int* __restrict__ bsum, int n){
  int b = blockIdx.x, t = threadIdx.x;
  int i = b*256 + t;
  if (i < n) rowstart[i+1] += bsum[b];
  if (i == 0) rowstart[0] = 0;
}

// ---------------- scatter edges into CSR (by dst, stores src) ----------------
__global__ void k_fill(const int* __restrict__ ei, int E, int n,
                       const int* __restrict__ rowstart, int* __restrict__ cur, int* __restrict__ csr){
  int i = blockIdx.x*blockDim.x + threadIdx.x;
  int tot = E + n;
  if (i >= tot) return;
  int src, dst;
  if (i < E){ src = ei[i]; dst = ei[E+i]; } else { src = i - E; dst = src; }
  int pos = atomicAdd(&cur[dst], 1);
  csr[rowstart[dst] + pos] = src;
}

// ---------------- GEMM1 (bf16 MFMA): xb[M,512] @ w1t[256,512]^T -> h1b[M,256] bf16 ----
__global__ __launch_bounds__(256) void k_gemm1_mfma(const unsigned short* __restrict__ A,
                                                    const unsigned short* __restrict__ BT,
                                                    unsigned short* __restrict__ Cb, int M){
  __shared__ __align__(16) unsigned short lA[4*128*8];  // 8 KB
  __shared__ __align__(16) unsigned short lB[4*128*8];  // 8 KB
  const int t = threadIdx.x;
  const int lane = t & 63, w = t >> 6;
  const int wx = w & 1, wy = w >> 1;
  const int row0 = blockIdx.x * 128, col0 = blockIdx.y * 128;

  f32x4 acc[4][4];
  #pragma unroll
  for (int i=0;i<4;i++)
    #pragma unroll
    for (int j=0;j<4;j++)
      #pragma unroll
      for (int r=0;r<4;r++) acc[i][j][r] = 0.f;

  const int c0 = t, c1 = t + 256;
  const int r0 = c0 & 127, kq0 = c0 >> 7;
  const int r1 = c1 & 127, kq1 = c1 >> 7;
  const size_t gA0 = (size_t)min(row0 + r0, M-1)*512 + kq0*8;
  const size_t gA1 = (size_t)min(row0 + r1, M-1)*512 + kq1*8;
  const size_t gB0 = (size_t)(col0 + r0)*512 + kq0*8;
  const size_t gB1 = (size_t)(col0 + r1)*512 + kq1*8;

  const int kq = lane >> 4, li = lane & 15;

  for (int kt = 0; kt < 512; kt += 32){
    __builtin_amdgcn_global_load_lds((const __attribute__((address_space(1))) void*)(A + gA0 + kt),
        (__attribute__((address_space(3))) void*)&lA[c0*8], 16, 0, 0);
    __builtin_amdgcn_global_load_lds((const __attribute__((address_space(1))) void*)(A + gA1 + kt),
        (__attribute__((address_space(3))) void*)&lA[c1*8], 16, 0, 0);
    __builtin_amdgcn_global_load_lds((const __attribute__((address_space(1))) void*)(BT + gB0 + kt),
        (__attribute__((address_space(3))) void*)&lB[c0*8], 16, 0, 0);
    __builtin_amdgcn_global_load_lds((const __attribute__((address_space(1))) void*)(BT + gB1 + kt),
        (__attribute__((address_space(3))) void*)&lB[c1*8], 16, 0, 0);
    __syncthreads();

    bf16x8 af[4], bfr[4];
    #pragma unroll
    for (int i=0;i<4;i++){
      af[i]  = *(const bf16x8*)&lA[(kq*128 + wx*64 + i*16 + li)*8];
      bfr[i] = *(const bf16x8*)&lB[(kq*128 + wy*64 + i*16 + li)*8];
    }
    #pragma unroll
    for (int i=0;i<4;i++)
      #pragma unroll
      for (int j=0;j<4;j++)
        acc[i][j] = __builtin_amdgcn_mfma_f32_16x16x32_bf16(af[i], bfr[j], acc[i][j], 0, 0, 0);
    __syncthreads();
  }

  // epilogue: C/D map col=lane&15, row=(lane>>4)*4+reg ; store bf16
  #pragma unroll
  for (int i=0;i<4;i++){
    #pragma unroll
    for (int r=0;r<4;r++){
      int row = row0 + wx*64 + i*16 + kq*4 + r;
      if (row < M){
        #pragma unroll
        for (int j=0;j<4;j++)
          Cb[(size_t)row*256 + col0 + wy*64 + j*16 + li] = f2bf(acc[i][j][r]);
      }
    }
  }
}

// ---------------- attention coefficients L1: a_s/a_d [N,4] (bf16 h1) ----------------
__global__ __launch_bounds__(256) void k_att1(const unsigned short* __restrict__ h1b,
    const float* __restrict__ sw, const float* __restrict__ dw,
    float* __restrict__ as1, float* __restrict__ ad1, int n){
  int lane = threadIdx.x & 63;
  int node = blockIdx.x*4 + (threadIdx.x >> 6);
  if (node >= n) return;
  ushort4 hu = *(const ushort4*)(h1b + (size_t)node*256 + lane*4);
  float hx=bf2f(hu.x), hy=bf2f(hu.y), hz=bf2f(hu.z), hw=bf2f(hu.w);
  float4 sv = *(const float4*)(sw + lane*4);
  float4 dv = *(const float4*)(dw + lane*4);
  float ps = hx*sv.x + hy*sv.y + hz*sv.z + hw*sv.w;
  float pd = hx*dv.x + hy*dv.y + hz*dv.z + hw*dv.w;
  #pragma unroll
  for (int o=1;o<16;o<<=1){ ps += __shfl_xor(ps,o); pd += __shfl_xor(pd,o); }
  if ((lane & 15) == 0){
    int h = lane >> 4;
    as1[node*4+h] = ps;
    ad1[node*4+h] = pd;
  }
}

// ---------------- aggregation L1 (softmax over in-edges) + bias + ELU -> bf16 ----------
__global__ __launch_bounds__(256) void k_agg1(const unsigned short* __restrict__ h1b,
    const float* __restrict__ as1, const float* __restrict__ ad1,
    const int* __restrict__ rowstart, const int* __restrict__ csr,
    const float* __restrict__ b1, unsigned short* __restrict__ hactb, int n){
  int lane = threadIdx.x & 63;
  int node = blockIdx.x*4 + (threadIdx.x >> 6);
  if (node >= n) return;
  int lo = rowstart[node], hi = rowstart[node+1];
  float4 adv = *(const float4*)(ad1 + node*4);
  float m0=-INFINITY, m1=-INFINITY, m2=-INFINITY, m3=-INFINITY;
  for (int e = lo + lane; e < hi; e += 64){
    int s = csr[e];
    float4 asv = *(const float4*)(as1 + s*4);
    m0 = fmaxf(m0, leaky(asv.x + adv.x));
    m1 = fmaxf(m1, leaky(asv.y + adv.y));
    m2 = fmaxf(m2, leaky(asv.z + adv.z));
    m3 = fmaxf(m3, leaky(asv.w + adv.w));
  }
  #pragma unroll
  for (int o=1;o<64;o<<=1){
    m0 = fmaxf(m0, __shfl_xor(m0,o));
    m1 = fmaxf(m1, __shfl_xor(m1,o));
    m2 = fmaxf(m2, __shfl_xor(m2,o));
    m3 = fmaxf(m3, __shfl_xor(m3,o));
  }
  int h = lane >> 4;                         // head of this lane's 4 channels
  float mh  = (h==0)?m0:(h==1)?m1:(h==2)?m2:m3;
  float adh = (h==0)?adv.x:(h==1)?adv.y:(h==2)?adv.z:adv.w;
  float ax=0.f, ay=0.f, az=0.f, aw=0.f, ssum=0.f;
  int e = lo;
  for (; e + 3 < hi; e += 4){                // 4-edge unroll: 4x gathers in flight
    int s0 = csr[e], s1 = csr[e+1], s2 = csr[e+2], s3 = csr[e+3];
    float x0 = __expf(leaky(as1[s0*4+h] + adh) - mh);
    float x1 = __expf(leaky(as1[s1*4+h] + adh) - mh);
    float x2 = __expf(leaky(as1[s2*4+h] + adh) - mh);
    float x3 = __expf(leaky(as1[s3*4+h] + adh) - mh);
    ushort4 u0 = *(const ushort4*)(h1b + (size_t)s0*256 + lane*4);
    ushort4 u1 = *(const ushort4*)(h1b + (size_t)s1*256 + lane*4);
    ushort4 u2 = *(const ushort4*)(h1b + (size_t)s2*256 + lane*4);
    ushort4 u3 = *(const ushort4*)(h1b + (size_t)s3*256 + lane*4);
    ax += x0*bf2f(u0.x) + x1*bf2f(u1.x) + x2*bf2f(u2.x) + x3*bf2f(u3.x);
    ay += x0*bf2f(u0.y) + x1*bf2f(u1.y) + x2*bf2f(u2.y) + x3*bf2f(u3.y);
    az += x0*bf2f(u0.z) + x1*bf2f(u1.z) + x2*bf2f(u2.z) + x3*bf2f(u3.z);
    aw += x0*bf2f(u0.w) + x1*bf2f(u1.w) + x2*bf2f(u2.w) + x3*bf2f(u3.w);
    ssum += x0 + x1 + x2 + x3;
  }
  for (; e < hi; ++e){
    int s0 = csr[e];
    float x0 = __expf(leaky(as1[s0*4+h] + adh) - mh);
    ushort4 u0 = *(const ushort4*)(h1b + (size_t)s0*256 + lane*4);
    ax += x0*bf2f(u0.x); ay += x0*bf2f(u0.y); az += x0*bf2f(u0.z); aw += x0*bf2f(u0.w);
    ssum += x0;
  }
  float inv = 1.f/(ssum + 1e-16f);
  float4 bv = *(const float4*)(b1 + lane*4);
  float o0 = ax*inv + bv.x, o1 = ay*inv + bv.y, o2 = az*inv + bv.z, o3 = aw*inv + bv.w;
  ushort4 r;
  r.x = f2bf(o0 > 0.f ? o0 : expm1f(o0));
  r.y = f2bf(o1 > 0.f ? o1 : expm1f(o1));
  r.z = f2bf(o2 > 0.f ? o2 : expm1f(o2));
  r.w = f2bf(o3 > 0.f ? o3 : expm1f(o3));
  *(ushort4*)(hactb + (size_t)node*256 + lane*4) = r;
}

// ---------------- GEMM2: hact[M,256]bf16 @ W2[256,40]f32 -> h2b[M,40]bf16 ------------
// + fused att2: as2/ad2 [N] via LDS reduce.
__global__ __launch_bounds__(256) void k_gemm2(const unsigned short* __restrict__ A,
    const float* __restrict__ B, const float* __restrict__ sw, const float* __restrict__ dw,
    unsigned short* __restrict__ Cb, float* __restrict__ as2, float* __restrict__ ad2, int M){
  __shared__ float Xl[32][129];       // pad -> conflict-free column reads
  __shared__ float Wl[128*40];
  __shared__ float Sps[32][8], Spd[32][8];
  int t = threadIdx.x;
  int row0 = blockIdx.x*32;
  int r = t & 31, g = t >> 5;         // g in 0..7 -> cols g*5 .. g*5+4
  float acc[5] = {0,0,0,0,0};
  for (int kt=0; kt<256; kt+=128){
    for (int i=t; i<1280; i+=256)
      *(float4*)&Wl[i*4] = *(const float4*)(B + kt*40 + i*4);
    for (int i=t; i<512; i+=256){     // 32 rows x 128 k, 8 bf16 per chunk
      int rr = i >> 4, k8 = i & 15;
      int grow = row0 + rr; if (grow >= M) grow = M-1;
      uint4 v = *(const uint4*)(A + (size_t)grow*256 + kt + k8*8);
      float* xp = &Xl[rr][k8*8];
      xp[0] = __uint_as_float(v.x << 16); xp[1] = __uint_as_float(v.x & 0xffff0000u);
      xp[2] = __uint_as_float(v.y << 16); xp[3] = __uint_as_float(v.y & 0xffff0000u);
      xp[4] = __uint_as_float(v.z << 16); xp[5] = __uint_as_float(v.z & 0xffff0000u);
      xp[6] = __uint_as_float(v.w << 16); xp[7] = __uint_as_float(v.w & 0xffff0000u);
    }
    __syncthreads();
    #pragma unroll 4
    for (int k=0;k<128;++k){
      float a = Xl[r][k];
      const float* wp = &Wl[k*40 + g*5];
      #pragma unroll
      for (int j=0;j<5;++j) acc[j] += a * wp[j];
    }
    __syncthreads();
  }
  int grow = row0 + r;
  float ps = 0.f, pd = 0.f;
  #pragma unroll
  for (int j=0;j<5;++j){
    ps += acc[j] * sw[g*5+j];
    pd += acc[j] * dw[g*5+j];
  }
  Sps[r][g] = ps; Spd[r][g] = pd;
  if (grow < M){
    #pragma unroll
    for (int j=0;j<5;++j) Cb[(size_t)grow*40 + g*5 + j] = f2bf(acc[j]);
  }
  __syncthreads();
  if (t < 32){
    float a = 0.f, b = 0.f;
    #pragma unroll
    for (int g2=0; g2<8; ++g2){ a += Sps[t][g2]; b += Spd[t][g2]; }
    int rw = row0 + t;
    if (rw < M){ as2[rw] = a; ad2[rw] = b; }
  }
}

// ---------------- aggregation L2 + bias + log_softmax -> out ----------------
// Chunk-broadcast: logits/exp computed lane-parallel, gather loop unrolled x4.
__global__ __launch_bounds__(256) void k_agg2(const unsigned short* __restrict__ h2b,
    const float* __restrict__ as2, const float* __restrict__ ad2,
    const int* __restrict__ rowstart, const int* __restrict__ csr,
    const float* __restrict__ b2, float* __restrict__ out, int n){
  int lane = threadIdx.x & 63;
  int node = blockIdx.x*4 + (threadIdx.x >> 6);
  if (node >= n) return;
  int lo = rowstart[node], hi = rowstart[node+1];
  int deg = hi - lo;
  float adn = ad2[node];
  // pass 1: lane-parallel logits; cache first chunk's (src, logit) in regs
  int   sl = 0;
  float ll = -INFINITY;
  if (lane < deg){ sl = csr[lo + lane]; ll = leaky(as2[sl] + adn); }
  float m = ll;
  for (int e = lo + lane + 64; e < hi; e += 64)
    m = fmaxf(m, leaky(as2[csr[e]] + adn));
  #pragma unroll
  for (int o=1;o<64;o<<=1) m = fmaxf(m, __shfl_xor(m,o));

  bool act = lane < 40;
  float acc = 0.f, psum = 0.f;
  for (int c = lo; c < hi; c += 64){
    int cnt = min(64, hi - c);
    int   s_l; float ex_l;
    if (c == lo){
      s_l = sl; ex_l = (lane < cnt) ? __expf(ll - m) : 0.f;
    } else {
      s_l = 0; ex_l = 0.f;
      if (lane < cnt){ s_l = csr[c + lane]; ex_l = __expf(leaky(as2[s_l] + adn) - m); }
    }
    psum += ex_l;
    int j = 0;
    for (; j + 3 < cnt; j += 4){
      int   s0=__shfl(s_l,j),  s1=__shfl(s_l,j+1),  s2=__shfl(s_l,j+2),  s3=__shfl(s_l,j+3);
      float e0=__shfl(ex_l,j), e1=__shfl(ex_l,j+1), e2=__shfl(ex_l,j+2), e3=__shfl(ex_l,j+3);
      float h0 = act ? bf2f(h2b[(size_t)s0*40 + lane]) : 0.f;
      float h1 = act ? bf2f(h2b[(size_t)s1*40 + lane]) : 0.f;
      float h2 = act ? bf2f(h2b[(size_t)s2*40 + lane]) : 0.f;
      float h3 = act ? bf2f(h2b[(size_t)s3*40 + lane]) : 0.f;
      acc += e0*h0; acc += e1*h1; acc += e2*h2; acc += e3*h3;
    }
    for (; j < cnt; ++j){
      int s0=__shfl(s_l,j); float e0=__shfl(ex_l,j);
      acc += e0 * (act ? bf2f(h2b[(size_t)s0*40 + lane]) : 0.f);
    }
  }
  float ssum = psum;
  #pragma unroll
  for (int o=1;o<64;o<<=1) ssum += __shfl_xor(ssum,o);
  float ov = acc/(ssum + 1e-16f) + (act ? b2[lane] : 0.f);
  float v = act ? ov : -INFINITY;
  float mx = v;
  #pragma unroll
  for (int o=1;o<64;o<<=1) mx = fmaxf(mx, __shfl_xor(mx,o));
  float ev = act ? __expf(ov - mx) : 0.f;
  float se = ev;
  #pragma unroll
  for (int o=1;o<64;o<<=1) se += __shfl_xor(se,o);
  if (act) out[(size_t)node*40 + lane] = (ov - mx) - __logf(se);
}

extern "C" void kernel_launch(void* const* d_in, const int* in_sizes, int n_in,
                              void* d_out, int out_size, void* d_ws, size_t ws_size,
                              hipStream_t stream){
  const float* x   = (const float*)d_in[0];
  const int*   ei  = (const int*)d_in[1];     // [2,E] int32 (harness contract)
  const float* W1  = (const float*)d_in[2];
  const float* s1w = (const float*)d_in[3];
  const float* d1w = (const float*)d_in[4];
  const float* b1  = (const float*)d_in[5];
  const float* W2  = (const float*)d_in[6];
  const float* s2w = (const float*)d_in[7];
  const float* d2w = (const float*)d_in[8];
  const float* b2  = (const float*)d_in[9];
  float* out = (float*)d_out;

  const int N  = in_sizes[0] / 512;
  const int E  = in_sizes[1] / 2;
  const int Et = E + N;

  // workspace carve-out (~110 MB)
  float* f = (float*)d_ws;
  unsigned short* h1b   = (unsigned short*)f;  f += (size_t)N*128;   // [N][256] bf16
  unsigned short* hactb = (unsigned short*)f;  f += (size_t)N*128;   // [N][256] bf16
  float* as1  = f;  f += (size_t)N*4;
  float* ad1  = f;  f += (size_t)N*4;
  float* as2  = f;  f += N;
  float* ad2  = f;  f += N;
  unsigned short* w1t = (unsigned short*)f;  f += 256*512/2;         // [256][512] bf16
  unsigned short* xb  = (unsigned short*)f;  f += (size_t)N*256;     // [N][512] bf16
  unsigned short* h2b = xb;                  // alias: xb dead after gemm1
  int* ip = (int*)f;
  int* rowstart = ip;  ip += (N + 4) & ~3;
  int* deg      = ip;  ip += N;              // deg+cur adjacent -> single memset
  int* cur      = ip;  ip += N;
  int* csr      = ip;  ip += Et;
  int* bsum     = ip;  ip += 256;

  int nb4 = (N + 3) / 4;
  int n4  = (N*512)/4;
  int nbs = (N + 255) / 256;                 // scan blocks (196 <= 256)
  k_cvt_x<<<(n4+255)/256, 256, 0, stream>>>(x, xb, n4);
  k_cvt_w<<<512, 256, 0, stream>>>(W1, w1t);
  hipMemsetAsync(deg, 0, (size_t)2*N*sizeof(int), stream);
  k_count<<<(Et+255)/256, 256, 0, stream>>>(ei, E, N, deg);
  k_scan_a<<<nbs, 256, 0, stream>>>(deg, rowstart, bsum, N);
  k_scan_b<<<1, 256, 0, stream>>>(bsum, nbs);
  k_scan_c<<<nbs, 256, 0, stream>>>(rowstart, bsum, N);
  k_fill <<<(Et+255)/256, 256, 0, stream>>>(ei, E, N, rowstart, cur, csr);
  k_gemm1_mfma<<<dim3((N+127)/128, 2), 256, 0, stream>>>(xb, w1t, h1b, N);
  k_att1 <<<nb4, 256, 0, stream>>>(h1b, s1w, d1w, as1, ad1, N);
  k_agg1 <<<nb4, 256, 0, stream>>>(h1b, as1, ad1, rowstart, csr, b1, hactb, N);
  k_gemm2<<<(N+31)/32, 256, 0, stream>>>(hactb, W2, s2w, d2w, h2b, as2, ad2, N);
  k_agg2 <<<nb4, 256, 0, stream>>>(h2b, as2, ad2, rowstart, csr, b2, out, N);
}

// Round 6
// 474.226 us; speedup vs baseline: 1.6290x; 1.0295x over previous
//
#include <hip/hip_runtime.h>
#include <math.h>
#include <stdint.h>

// GAT 2-layer: N=50000 nodes, E=800000 edges (+N self loops)
// L1: 512 -> 4 heads x 64 (bf16 MFMA GEMM, att1 fused in epilogue), ELU.
// L2: 256 -> 1 head x 40 (att2 fused in gemm2), log_softmax.
// All intermediate node features (h1, hact, h2) stored bf16; accumulation fp32.

typedef short bf16x8 __attribute__((ext_vector_type(8)));
typedef float f32x4  __attribute__((ext_vector_type(4)));

static __device__ __forceinline__ float leaky(float x){ return x > 0.f ? x : 0.2f*x; }
static __device__ __forceinline__ unsigned short f2bf(float f){
  uint32_t u = __float_as_uint(f);
  uint32_t r = u + 0x7fffu + ((u >> 16) & 1u);   // RNE
  return (unsigned short)(r >> 16);
}
static __device__ __forceinline__ float bf2f(unsigned short u){
  return __uint_as_float(((uint32_t)u) << 16);
}

// ---------------- convert x -> bf16 (vectorized) ----------------
__global__ void k_cvt_x(const float* __restrict__ x, unsigned short* __restrict__ xb, int n4){
  int i = blockIdx.x*blockDim.x + threadIdx.x;
  if (i >= n4) return;
  float4 v = ((const float4*)x)[i];
  ushort4 o; o.x=f2bf(v.x); o.y=f2bf(v.y); o.z=f2bf(v.z); o.w=f2bf(v.w);
  ((ushort4*)xb)[i] = o;
}

// ---------------- convert+transpose W1[512][256] -> w1t[256][512] bf16 ----------------
__global__ void k_cvt_w(const float* __restrict__ W, unsigned short* __restrict__ wt){
  int i = blockIdx.x*blockDim.x + threadIdx.x;   // 0..131071
  if (i >= 512*256) return;
  int k = i >> 8, n = i & 255;
  wt[n*512 + k] = f2bf(W[i]);
}

// ---------------- count in-degree (incl self loops) ----------------
__global__ void k_count(const int* __restrict__ ei, int E, int n, int* __restrict__ deg){
  int i = blockIdx.x*blockDim.x + threadIdx.x;
  int tot = E + n;
  if (i >= tot) return;
  int dst = (i < E) ? ei[E + i] : (i - E);
  atomicAdd(&deg[dst], 1);
}

// ---------------- multi-block exclusive scan: deg[n] -> rowstart[0..n] ----------------
__global__ __launch_bounds__(256) void k_scan_a(const int* __restrict__ deg,
    int* __restrict__ rowstart, int* __restrict__ bsum, int n){
  __shared__ int sm[256];
  int b = blockIdx.x, t = threadIdx.x;
  int i = b*256 + t;
  int v = (i < n) ? deg[i] : 0;
  sm[t] = v;
  __syncthreads();
  for (int off=1; off<256; off<<=1){
    int u = (t >= off) ? sm[t-off] : 0;
    __syncthreads();
    sm[t] += u;
    __syncthreads();
  }
  if (i < n) rowstart[i+1] = sm[t];
  if (t == 255) bsum[b] = sm[255];
}
__global__ __launch_bounds__(256) void k_scan_b(int* __restrict__ bsum, int nb){
  __shared__ int sm[256];
  int t = threadIdx.x;
  int v = (t < nb) ? bsum[t] : 0;
  sm[t] = v;
  __syncthreads();
  for (int off=1; off<256; off<<=1){
    int u = (t >= off) ? sm[t-off] : 0;
    __syncthreads();
    sm[t] += u;
    __syncthreads();
  }
  if (t < nb) bsum[t] = sm[t] - v;   // exclusive prefix
}
__global__ __launch_bounds__(256) void k_scan_c(int* __restrict__ rowstart,
    const int* __restrict__ bsum, int n){
  int b = blockIdx.x, t = threadIdx.x;
  int i = b*256 + t;
  if (i < n) rowstart[i+1] += bsum[b];
  if (i == 0) rowstart[0] = 0;
}

// ---------------- scatter edges into CSR (by dst, stores src) ----------------
__global__ void k_fill(const int* __restrict__ ei, int E, int n,
                       const int* __restrict__ rowstart, int* __restrict__ cur, int* __restrict__ csr){
  int i = blockIdx.x*blockDim.x + threadIdx.x;
  int tot = E + n;
  if (i >= tot) return;
  int src, dst;
  if (i < E){ src = ei[i]; dst = ei[E+i]; } else { src = i - E; dst = src; }
  int pos = atomicAdd(&cur[dst], 1);
  csr[rowstart[dst] + pos] = src;
}

// ---------------- GEMM1 (bf16 MFMA) + fused att1 ----------------
// xb[M,512] @ w1t[256,512]^T -> h1b[M,256] bf16; as1/ad1[M,4] from fp32 acc.
// Each wave's 64-col span = exactly one head (hw = by*2 + wy).
__global__ __launch_bounds__(256) void k_gemm1_mfma(const unsigned short* __restrict__ A,
                                                    const unsigned short* __restrict__ BT,
                                                    const float* __restrict__ SW,
                                                    const float* __restrict__ DW,
                                                    unsigned short* __restrict__ Cb,
                                                    float* __restrict__ as1,
                                                    float* __restrict__ ad1, int M){
  __shared__ __align__(16) unsigned short lA[4*128*8];  // 8 KB
  __shared__ __align__(16) unsigned short lB[4*128*8];  // 8 KB
  const int t = threadIdx.x;
  const int lane = t & 63, w = t >> 6;
  const int wx = w & 1, wy = w >> 1;
  const int row0 = blockIdx.x * 128, col0 = blockIdx.y * 128;

  f32x4 acc[4][4];
  #pragma unroll
  for (int i=0;i<4;i++)
    #pragma unroll
    for (int j=0;j<4;j++)
      #pragma unroll
      for (int r=0;r<4;r++) acc[i][j][r] = 0.f;

  const int c0 = t, c1 = t + 256;
  const int r0 = c0 & 127, kq0 = c0 >> 7;
  const int r1 = c1 & 127, kq1 = c1 >> 7;
  const size_t gA0 = (size_t)min(row0 + r0, M-1)*512 + kq0*8;
  const size_t gA1 = (size_t)min(row0 + r1, M-1)*512 + kq1*8;
  const size_t gB0 = (size_t)(col0 + r0)*512 + kq0*8;
  const size_t gB1 = (size_t)(col0 + r1)*512 + kq1*8;

  const int kq = lane >> 4, li = lane & 15;

  for (int kt = 0; kt < 512; kt += 32){
    __builtin_amdgcn_global_load_lds((const __attribute__((address_space(1))) void*)(A + gA0 + kt),
        (__attribute__((address_space(3))) void*)&lA[c0*8], 16, 0, 0);
    __builtin_amdgcn_global_load_lds((const __attribute__((address_space(1))) void*)(A + gA1 + kt),
        (__attribute__((address_space(3))) void*)&lA[c1*8], 16, 0, 0);
    __builtin_amdgcn_global_load_lds((const __attribute__((address_space(1))) void*)(BT + gB0 + kt),
        (__attribute__((address_space(3))) void*)&lB[c0*8], 16, 0, 0);
    __builtin_amdgcn_global_load_lds((const __attribute__((address_space(1))) void*)(BT + gB1 + kt),
        (__attribute__((address_space(3))) void*)&lB[c1*8], 16, 0, 0);
    __syncthreads();

    bf16x8 af[4], bfr[4];
    #pragma unroll
    for (int i=0;i<4;i++){
      af[i]  = *(const bf16x8*)&lA[(kq*128 + wx*64 + i*16 + li)*8];
      bfr[i] = *(const bf16x8*)&lB[(kq*128 + wy*64 + i*16 + li)*8];
    }
    #pragma unroll
    for (int i=0;i<4;i++)
      #pragma unroll
      for (int j=0;j<4;j++)
        acc[i][j] = __builtin_amdgcn_mfma_f32_16x16x32_bf16(af[i], bfr[j], acc[i][j], 0, 0, 0);
    __syncthreads();
  }

  // epilogue 1: C store. C/D map col=lane&15, row=(lane>>4)*4+reg
  #pragma unroll
  for (int i=0;i<4;i++){
    #pragma unroll
    for (int r=0;r<4;r++){
      int row = row0 + wx*64 + i*16 + kq*4 + r;
      if (row < M){
        #pragma unroll
        for (int j=0;j<4;j++)
          Cb[(size_t)row*256 + col0 + wy*64 + j*16 + li] = f2bf(acc[i][j][r]);
      }
    }
  }

  // epilogue 2: fused att1 dots for head hw (this wave's 64-col span)
  const int hw = (int)blockIdx.y*2 + wy;
  float sv[4], dv[4];
  #pragma unroll
  for (int j=0;j<4;j++){
    sv[j] = SW[hw*64 + j*16 + li];
    dv[j] = DW[hw*64 + j*16 + li];
  }
  #pragma unroll
  for (int i=0;i<4;i++){
    #pragma unroll
    for (int r=0;r<4;r++){
      float ps = acc[i][0][r]*sv[0] + acc[i][1][r]*sv[1] + acc[i][2][r]*sv[2] + acc[i][3][r]*sv[3];
      float pd = acc[i][0][r]*dv[0] + acc[i][1][r]*dv[1] + acc[i][2][r]*dv[2] + acc[i][3][r]*dv[3];
      #pragma unroll
      for (int o=1;o<16;o<<=1){ ps += __shfl_xor(ps,o); pd += __shfl_xor(pd,o); }
      int row = row0 + wx*64 + i*16 + kq*4 + r;
      if (li == 0 && row < M){
        as1[row*4 + hw] = ps;
        ad1[row*4 + hw] = pd;
      }
    }
  }
}

// ---------------- aggregation L1 (softmax over in-edges) + bias + ELU -> bf16 ----------
// Chunk-broadcast: logits/exp lane-parallel with (edge,head)=(lane>>2,lane&3) layout;
// gather loop = shfl-broadcast + ushort4 load + fma, unrolled x4.
__global__ __launch_bounds__(256) void k_agg1(const unsigned short* __restrict__ h1b,
    const float* __restrict__ as1, const float* __restrict__ ad1,
    const int* __restrict__ rowstart, const int* __restrict__ csr,
    const float* __restrict__ b1, unsigned short* __restrict__ hactb, int n){
  int lane = threadIdx.x & 63;
  int node = blockIdx.x*4 + (threadIdx.x >> 6);
  if (node >= n) return;
  int lo = rowstart[node], hi = rowstart[node+1];
  int jj = lane >> 2, hh = lane & 3;           // pass layout: 16 edges x 4 heads
  float adh_p = ad1[node*4 + hh];

  // pass 1: max over edges, lane-parallel
  float m = -INFINITY;
  for (int c = lo + jj; c < hi; c += 16){
    int s = csr[c];
    m = fmaxf(m, leaky(as1[s*4 + hh] + adh_p));
  }
  #pragma unroll
  for (int o=4;o<64;o<<=1) m = fmaxf(m, __shfl_xor(m,o));   // reduce within head class

  int h = lane >> 4;                            // gather layout: head of lane's 4 channels
  float ax=0.f, ay=0.f, az=0.f, aw=0.f, psum=0.f;
  for (int c = lo; c < hi; c += 16){
    int cnt = min(16, hi - c);
    int s_l = 0; float ex_l = 0.f;
    if (jj < cnt){
      s_l = csr[c + jj];
      ex_l = __expf(leaky(as1[s_l*4 + hh] + adh_p) - m);
    }
    psum += ex_l;
    int j = 0;
    for (; j + 3 < cnt; j += 4){
      int   s0 = __shfl(s_l, j*4),      s1 = __shfl(s_l, j*4+4),
            s2 = __shfl(s_l, j*4+8),    s3 = __shfl(s_l, j*4+12);
      float e0 = __shfl(ex_l, j*4+h),   e1 = __shfl(ex_l, j*4+4+h),
            e2 = __shfl(ex_l, j*4+8+h), e3 = __shfl(ex_l, j*4+12+h);
      ushort4 u0 = *(const ushort4*)(h1b + (size_t)s0*256 + lane*4);
      ushort4 u1 = *(const ushort4*)(h1b + (size_t)s1*256 + lane*4);
      ushort4 u2 = *(const ushort4*)(h1b + (size_t)s2*256 + lane*4);
      ushort4 u3 = *(const ushort4*)(h1b + (size_t)s3*256 + lane*4);
      ax += e0*bf2f(u0.x) + e1*bf2f(u1.x) + e2*bf2f(u2.x) + e3*bf2f(u3.x);
      ay += e0*bf2f(u0.y) + e1*bf2f(u1.y) + e2*bf2f(u2.y) + e3*bf2f(u3.y);
      az += e0*bf2f(u0.z) + e1*bf2f(u1.z) + e2*bf2f(u2.z) + e3*bf2f(u3.z);
      aw += e0*bf2f(u0.w) + e1*bf2f(u1.w) + e2*bf2f(u2.w) + e3*bf2f(u3.w);
    }
    for (; j < cnt; ++j){
      int   s0 = __shfl(s_l, j*4);
      float e0 = __shfl(ex_l, j*4+h);
      ushort4 u0 = *(const ushort4*)(h1b + (size_t)s0*256 + lane*4);
      ax += e0*bf2f(u0.x); ay += e0*bf2f(u0.y); az += e0*bf2f(u0.z); aw += e0*bf2f(u0.w);
    }
  }
  // denominator: reduce psum within head class, then broadcast to gather lanes
  #pragma unroll
  for (int o=4;o<64;o<<=1) psum += __shfl_xor(psum,o);
  float ssum = __shfl(psum, h);                 // lane h (0..3) holds class h
  float inv = 1.f/(ssum + 1e-16f);
  float4 bv = *(const float4*)(b1 + lane*4);
  float o0 = ax*inv + bv.x, o1 = ay*inv + bv.y, o2 = az*inv + bv.z, o3 = aw*inv + bv.w;
  ushort4 r;
  r.x = f2bf(o0 > 0.f ? o0 : expm1f(o0));
  r.y = f2bf(o1 > 0.f ? o1 : expm1f(o1));
  r.z = f2bf(o2 > 0.f ? o2 : expm1f(o2));
  r.w = f2bf(o3 > 0.f ? o3 : expm1f(o3));
  *(ushort4*)(hactb + (size_t)node*256 + lane*4) = r;
}

// ---------------- GEMM2: hact[M,256]bf16 @ W2[256,40]f32 -> h2b[M,40]bf16 ------------
// + fused att2: as2/ad2 [N] via LDS reduce.
__global__ __launch_bounds__(256) void k_gemm2(const unsigned short* __restrict__ A,
    const float* __restrict__ B, const float* __restrict__ sw, const float* __restrict__ dw,
    unsigned short* __restrict__ Cb, float* __restrict__ as2, float* __restrict__ ad2, int M){
  __shared__ float Xl[32][129];       // pad -> conflict-free column reads
  __shared__ float Wl[128*40];
  __shared__ float Sps[32][8], Spd[32][8];
  int t = threadIdx.x;
  int row0 = blockIdx.x*32;
  int r = t & 31, g = t >> 5;         // g in 0..7 -> cols g*5 .. g*5+4
  float acc[5] = {0,0,0,0,0};
  for (int kt=0; kt<256; kt+=128){
    for (int i=t; i<1280; i+=256)
      *(float4*)&Wl[i*4] = *(const float4*)(B + kt*40 + i*4);
    for (int i=t; i<512; i+=256){     // 32 rows x 128 k, 8 bf16 per chunk
      int rr = i >> 4, k8 = i & 15;
      int grow = row0 + rr; if (grow >= M) grow = M-1;
      uint4 v = *(const uint4*)(A + (size_t)grow*256 + kt + k8*8);
      float* xp = &Xl[rr][k8*8];
      xp[0] = __uint_as_float(v.x << 16); xp[1] = __uint_as_float(v.x & 0xffff0000u);
      xp[2] = __uint_as_float(v.y << 16); xp[3] = __uint_as_float(v.y & 0xffff0000u);
      xp[4] = __uint_as_float(v.z << 16); xp[5] = __uint_as_float(v.z & 0xffff0000u);
      xp[6] = __uint_as_float(v.w << 16); xp[7] = __uint_as_float(v.w & 0xffff0000u);
    }
    __syncthreads();
    #pragma unroll 4
    for (int k=0;k<128;++k){
      float a = Xl[r][k];
      const float* wp = &Wl[k*40 + g*5];
      #pragma unroll
      for (int j=0;j<5;++j) acc[j] += a * wp[j];
    }
    __syncthreads();
  }
  int grow = row0 + r;
  float ps = 0.f, pd = 0.f;
  #pragma unroll
  for (int j=0;j<5;++j){
    ps += acc[j] * sw[g*5+j];
    pd += acc[j] * dw[g*5+j];
  }
  Sps[r][g] = ps; Spd[r][g] = pd;
  if (grow < M){
    #pragma unroll
    for (int j=0;j<5;++j) Cb[(size_t)grow*40 + g*5 + j] = f2bf(acc[j]);
  }
  __syncthreads();
  if (t < 32){
    float a = 0.f, b = 0.f;
    #pragma unroll
    for (int g2=0; g2<8; ++g2){ a += Sps[t][g2]; b += Spd[t][g2]; }
    int rw = row0 + t;
    if (rw < M){ as2[rw] = a; ad2[rw] = b; }
  }
}

// ---------------- aggregation L2 + bias + log_softmax -> out ----------------
__global__ __launch_bounds__(256) void k_agg2(const unsigned short* __restrict__ h2b,
    const float* __restrict__ as2, const float* __restrict__ ad2,
    const int* __restrict__ rowstart, const int* __restrict__ csr,
    const float* __restrict__ b2, float* __restrict__ out, int n){
  int lane = threadIdx.x & 63;
  int node = blockIdx.x*4 + (threadIdx.x >> 6);
  if (node >= n) return;
  int lo = rowstart[node], hi = rowstart[node+1];
  int deg = hi - lo;
  float adn = ad2[node];
  int   sl = 0;
  float ll = -INFINITY;
  if (lane < deg){ sl = csr[lo + lane]; ll = leaky(as2[sl] + adn); }
  float m = ll;
  for (int e = lo + lane + 64; e < hi; e += 64)
    m = fmaxf(m, leaky(as2[csr[e]] + adn));
  #pragma unroll
  for (int o=1;o<64;o<<=1) m = fmaxf(m, __shfl_xor(m,o));

  bool act = lane < 40;
  float acc = 0.f, psum = 0.f;
  for (int c = lo; c < hi; c += 64){
    int cnt = min(64, hi - c);
    int   s_l; float ex_l;
    if (c == lo){
      s_l = sl; ex_l = (lane < cnt) ? __expf(ll - m) : 0.f;
    } else {
      s_l = 0; ex_l = 0.f;
      if (lane < cnt){ s_l = csr[c + lane]; ex_l = __expf(leaky(as2[s_l] + adn) - m); }
    }
    psum += ex_l;
    int j = 0;
    for (; j + 3 < cnt; j += 4){
      int   s0=__shfl(s_l,j),  s1=__shfl(s_l,j+1),  s2=__shfl(s_l,j+2),  s3=__shfl(s_l,j+3);
      float e0=__shfl(ex_l,j), e1=__shfl(ex_l,j+1), e2=__shfl(ex_l,j+2), e3=__shfl(ex_l,j+3);
      float h0 = act ? bf2f(h2b[(size_t)s0*40 + lane]) : 0.f;
      float h1 = act ? bf2f(h2b[(size_t)s1*40 + lane]) : 0.f;
      float h2 = act ? bf2f(h2b[(size_t)s2*40 + lane]) : 0.f;
      float h3 = act ? bf2f(h2b[(size_t)s3*40 + lane]) : 0.f;
      acc += e0*h0; acc += e1*h1; acc += e2*h2; acc += e3*h3;
    }
    for (; j < cnt; ++j){
      int s0=__shfl(s_l,j); float e0=__shfl(ex_l,j);
      acc += e0 * (act ? bf2f(h2b[(size_t)s0*40 + lane]) : 0.f);
    }
  }
  float ssum = psum;
  #pragma unroll
  for (int o=1;o<64;o<<=1) ssum += __shfl_xor(ssum,o);
  float ov = acc/(ssum + 1e-16f) + (act ? b2[lane] : 0.f);
  float v = act ? ov : -INFINITY;
  float mx = v;
  #pragma unroll
  for (int o=1;o<64;o<<=1) mx = fmaxf(mx, __shfl_xor(mx,o));
  float ev = act ? __expf(ov - mx) : 0.f;
  float se = ev;
  #pragma unroll
  for (int o=1;o<64;o<<=1) se += __shfl_xor(se,o);
  if (act) out[(size_t)node*40 + lane] = (ov - mx) - __logf(se);
}

extern "C" void kernel_launch(void* const* d_in, const int* in_sizes, int n_in,
                              void* d_out, int out_size, void* d_ws, size_t ws_size,
                              hipStream_t stream){
  const float* x   = (const float*)d_in[0];
  const int*   ei  = (const int*)d_in[1];     // [2,E] int32 (harness contract)
  const float* W1  = (const float*)d_in[2];
  const float* s1w = (const float*)d_in[3];
  const float* d1w = (const float*)d_in[4];
  const float* b1  = (const float*)d_in[5];
  const float* W2  = (const float*)d_in[6];
  const float* s2w = (const float*)d_in[7];
  const float* d2w = (const float*)d_in[8];
  const float* b2  = (const float*)d_in[9];
  float* out = (float*)d_out;

  const int N  = in_sizes[0] / 512;
  const int E  = in_sizes[1] / 2;
  const int Et = E + N;

  // workspace carve-out (~110 MB)
  float* f = (float*)d_ws;
  unsigned short* h1b   = (unsigned short*)f;  f += (size_t)N*128;   // [N][256] bf16
  unsigned short* hactb = (unsigned short*)f;  f += (size_t)N*128;   // [N][256] bf16
  float* as1  = f;  f += (size_t)N*4;
  float* ad1  = f;  f += (size_t)N*4;
  float* as2  = f;  f += N;
  float* ad2  = f;  f += N;
  unsigned short* w1t = (unsigned short*)f;  f += 256*512/2;         // [256][512] bf16
  unsigned short* xb  = (unsigned short*)f;  f += (size_t)N*256;     // [N][512] bf16
  unsigned short* h2b = xb;                  // alias: xb dead after gemm1
  int* ip = (int*)f;
  int* rowstart = ip;  ip += (N + 4) & ~3;
  int* deg      = ip;  ip += N;              // deg+cur adjacent -> single memset
  int* cur      = ip;  ip += N;
  int* csr      = ip;  ip += Et;
  int* bsum     = ip;  ip += 256;

  int nb4 = (N + 3) / 4;
  int n4  = (N*512)/4;
  int nbs = (N + 255) / 256;                 // scan blocks (196 <= 256)
  k_cvt_x<<<(n4+255)/256, 256, 0, stream>>>(x, xb, n4);
  k_cvt_w<<<512, 256, 0, stream>>>(W1, w1t);
  hipMemsetAsync(deg, 0, (size_t)2*N*sizeof(int), stream);
  k_count<<<(Et+255)/256, 256, 0, stream>>>(ei, E, N, deg);
  k_scan_a<<<nbs, 256, 0, stream>>>(deg, rowstart, bsum, N);
  k_scan_b<<<1, 256, 0, stream>>>(bsum, nbs);
  k_scan_c<<<nbs, 256, 0, stream>>>(rowstart, bsum, N);
  k_fill <<<(Et+255)/256, 256, 0, stream>>>(ei, E, N, rowstart, cur, csr);
  k_gemm1_mfma<<<dim3((N+127)/128, 2), 256, 0, stream>>>(xb, w1t, s1w, d1w, h1b, as1, ad1, N);
  k_agg1 <<<nb4, 256, 0, stream>>>(h1b, as1, ad1, rowstart, csr, b1, hactb, N);
  k_gemm2<<<(N+31)/32, 256, 0, stream>>>(hactb, W2, s2w, d2w, h2b, as2, ad2, N);
  k_agg2 <<<nb4, 256, 0, stream>>>(h2b, as2, ad2, rowstart, csr, b2, out, N);
}